// Round 1
// 7309.679 us; speedup vs baseline: 1.1542x; 1.1542x over previous
//
#include <hip/hip_runtime.h>
#include <hip/hip_bf16.h>
#include <math.h>

// EquiformerV2 block, fp32 activations. Round 7: attention SO2-conv GEMMs moved to
// MFMA (bf16). Edge-parallel kernel batches 4 CSR-ordered edges -> 96 padded rows
// (6 MFMA row-tiles) stacked group-major {5,8,6} rows/edge; vv/oe GEMMs run on
// matrix cores with fragment-packed bf16 weights; light per-node gather does the
// winv rotate + accumulate. E=40000 edges, N=2000 nodes, C=64, L2=25, M2=19, NL=2.

#define NRBF 600
#define DIN 728
#define GPTS 288
#define MAXE 160

typedef __attribute__((ext_vector_type(8))) short bf16x8;
typedef __attribute__((ext_vector_type(4))) float f32x4;

__constant__ int d_mg[19] = {0,1,0,1,2,1,0,1,2,2,1,0,1,2,2,1,0,1,2};
__constant__ int d_loc[25] = {0,1,1,1,2,2,2,2,2,3,3,3,3,3,3,3,4,4,4,4,4,4,4,4,4};
// EB=4 group-major row layout: g0 rows 0..19 (pad to 32), g1 rows 32..63, g2 rows 64..87 (pad to 96)
__constant__ int d_row2e[96] = {
  0,0,0,0,0, 1,1,1,1,1, 2,2,2,2,2, 3,3,3,3,3, -1,-1,-1,-1,-1,-1,-1,-1,-1,-1,-1,-1,
  0,0,0,0,0,0,0,0, 1,1,1,1,1,1,1,1, 2,2,2,2,2,2,2,2, 3,3,3,3,3,3,3,3,
  0,0,0,0,0,0, 1,1,1,1,1,1, 2,2,2,2,2,2, 3,3,3,3,3,3, -1,-1,-1,-1,-1,-1,-1,-1};
__constant__ int d_row2m[96] = {
  0,2,6,11,16, 0,2,6,11,16, 0,2,6,11,16, 0,2,6,11,16, 0,0,0,0,0,0,0,0,0,0,0,0,
  1,3,5,7,10,12,15,17, 1,3,5,7,10,12,15,17, 1,3,5,7,10,12,15,17, 1,3,5,7,10,12,15,17,
  4,8,9,13,14,18, 4,8,9,13,14,18, 4,8,9,13,14,18, 4,8,9,13,14,18, 0,0,0,0,0,0,0,0};
// m -> (row base, per-edge stride) in the 96-row layout
__constant__ int d_m2base[19] = {0,32,1,33,64,34,2,35,65,66,36,3,37,67,68,38,4,39,69};
__constant__ int d_m2str[19]  = {5,8,5,8,6,8,5,8,6,6,8,5,8,6,6,8,5,8,6};

__device__ inline float silu_f(float v){ return v/(1.0f+__expf(-v)); }
__device__ inline float bf2f(unsigned short u){ return __uint_as_float(((unsigned)u)<<16); }
__device__ inline unsigned short f2bf(float f){
  unsigned b=__float_as_uint(f);
  return (unsigned short)((b + 0x7FFF + ((b>>16)&1)) >> 16);
}

__device__ inline void atomicMaxF(float* addr, float val){
  int* ia=(int*)addr;
  int old=*ia;
  while (__int_as_float(old) < val){
    int assumed=old;
    old = atomicCAS(ia, assumed, __float_as_int(val));
    if (old == assumed) break;
  }
}

// ---------------- CSR build ----------------
__global__ __launch_bounds__(256) void zero_cnt_kernel(int* cnt, int N){
  int i = blockIdx.x*256+threadIdx.x;
  if (i<N) cnt[i]=0;
}
__global__ __launch_bounds__(256) void csr_count_kernel(const int* __restrict__ rcv, int* cnt, int E){
  int i = blockIdx.x*256+threadIdx.x;
  if (i<E) atomicAdd(&cnt[rcv[i]],1);
}
__global__ __launch_bounds__(256) void csr_scan_kernel(const int* __restrict__ cnt,
    int* rowptr, int* fill, int N){
  __shared__ int s_part[256];
  int tid=threadIdx.x;
  int chunk=(N+255)/256;
  int lvals[12];
  int base=tid*chunk;
  int lsum=0;
  for (int i=0;i<chunk && i<12;i++){
    int v=(base+i<N)?cnt[base+i]:0;
    lvals[i]=lsum; lsum+=v;
  }
  s_part[tid]=lsum;
  __syncthreads();
  if (tid==0){
    int run=0;
    for (int t=0;t<256;t++){ int v=s_part[t]; s_part[t]=run; run+=v; }
  }
  __syncthreads();
  int off=s_part[tid];
  for (int i=0;i<chunk && i<12;i++){
    if (base+i<N){ rowptr[base+i]=off+lvals[i]; fill[base+i]=off+lvals[i]; }
  }
  if (tid==255) rowptr[N]=off+lsum;
}
__global__ __launch_bounds__(256) void csr_fill_kernel(const int* __restrict__ rcv,
    int* fill, int* eix, int E){
  int i = blockIdx.x*256+threadIdx.x;
  if (i<E){ int p=atomicAdd(&fill[rcv[i]],1); eix[p]=i; }
}

// ---------------- fused so2W@valW -> bf16 wsvb, MFMA-B-fragment packed ----------------
// frag layout: idx = ((kt*8+nt)*64 + lane)*8 + i ; k = kt*32 + (lane>>4)*8 + i ; col = nt*16 + (lane&15)
__global__ __launch_bounds__(256) void wsvb_kernel(const float* __restrict__ so2W,
    const float* __restrict__ valW, unsigned short* __restrict__ wsvb){
  int i=blockIdx.x/3, g=blockIdx.x%3;
  const float* A = so2W + (size_t)i*24576 + g*8192;   // [128][64]
  const float* B = valW + (size_t)i*24576 + g*8192;   // [64][128]
  unsigned short* C = wsvb + (size_t)blockIdx.x*16384;
  __shared__ float sB[8192];
  for (int j=threadIdx.x;j<2048;j+=256) ((float4*)sB)[j]=((const float4*)B)[j];
  __syncthreads();
  for (int idx=threadIdx.x; idx<16384; idx+=256){
    int k=idx>>7, j=idx&127;
    float acc=0;
    #pragma unroll 4
    for (int o=0;o<64;o++) acc += A[k*64+o]*sB[o*128+j];
    int pos = ((k>>5)*8 + (j>>4))*512 + (((k>>3)&3)*16 + (j&15))*8 + (k&7);
    C[pos]=f2bf(acc);
  }
}

// ---------------- projW -> bf16 [6][128][64], MFMA-B-fragment packed ----------------
__global__ __launch_bounds__(256) void projb_kernel(const float* __restrict__ pW,
    unsigned short* __restrict__ projb){
  const float* src = pW + (size_t)blockIdx.x*8192;
  unsigned short* dst = projb + (size_t)blockIdx.x*8192;
  for (int idx=threadIdx.x; idx<8192; idx+=256){
    int k=idx>>6, j=idx&63;
    int pos = ((k>>5)*4 + (j>>4))*512 + (((k>>3)&3)*16 + (j&15))*8 + (k&7);
    dst[pos]=f2bf(src[idx]);
  }
}

// ---------------- edge degree embedding, gather form (per node) ----------------
__global__ __launch_bounds__(256) void deg_gather_kernel(const float* __restrict__ ev,
    const float* __restrict__ ese, const int* __restrict__ nsp, const float* __restrict__ spe,
    const float* __restrict__ W1, const float* __restrict__ b1,
    const float* __restrict__ W2, const float* __restrict__ b2,
    const float* __restrict__ winv, const int* __restrict__ snd,
    const int* __restrict__ rowptr, const int* __restrict__ eix,
    float* __restrict__ x, int N){
  int n = blockIdx.x, tid = threadIdx.x;
  __shared__ float s_ee[4][DIN];
  __shared__ float s_h1[4][128];
  __shared__ float s_h2[4][1216];
  __shared__ float s_part[256][4];
  __shared__ float s_acc[1600];
  __shared__ float s_winv[475];
  __shared__ int s_eix[MAXE];
  __shared__ float s_d[4]; __shared__ int s_ss[4]; __shared__ int s_rs[4];
  int row0=rowptr[n];
  int cnt=rowptr[n+1]-row0; if (cnt>MAXE) cnt=MAXE;
  {
    float4 z={0,0,0,0};
    for (int j=tid;j<400;j+=256) ((float4*)s_acc)[j]=z;
    for (int j=tid;j<cnt;j+=256) s_eix[j]=eix[row0+j];
  }
  __syncthreads();
  int nq=(cnt+3)>>2;
  for (int q=0;q<nq;q++){
    int qb=q*4;
    int ne=cnt-qb; if (ne>4) ne=4;
    if (tid<4){
      int le=qb+tid;
      if (le<cnt){
        int e=s_eix[le];
        float vx=ev[3*e], vy=ev[3*e+1], vz=ev[3*e+2];
        s_d[tid]=sqrtf(vx*vx+vy*vy+vz*vz+1e-12f);
        s_ss[tid]=nsp[snd[e]];
        s_rs[tid]=nsp[n];
      } else { s_d[tid]=0.0f; s_ss[tid]=0; s_rs[tid]=0; }
    }
    __syncthreads();
    const float step = 5.0f/599.0f;
    const float inv_std = 1.0f/(2.0f*step);
    for (int j=tid;j<4*DIN;j+=256){
      int le=j/DIN, jj=j%DIN;
      float v;
      if (jj<NRBF){ float t=(s_d[le]-jj*step)*inv_std; v=__expf(-0.5f*t*t); }
      else if (jj<NRBF+64) v=ese[s_ss[le]*128+(jj-NRBF)];
      else v=ese[s_rs[le]*128+64+(jj-NRBF-64)];
      s_ee[le][jj]=v;
    }
    __syncthreads();
    {
      int o=tid&127, half=tid>>7, i0=half*364;
      float a0=0,a1=0,a2=0,a3=0;
      for (int i=i0;i<i0+364;i++){
        float w=W1[i*128+o];
        a0+=s_ee[0][i]*w; a1+=s_ee[1][i]*w; a2+=s_ee[2][i]*w; a3+=s_ee[3][i]*w;
      }
      s_part[tid][0]=a0; s_part[tid][1]=a1; s_part[tid][2]=a2; s_part[tid][3]=a3;
    }
    __syncthreads();
    if (tid<128){
      float bb=b1[tid];
      #pragma unroll
      for (int le=0;le<4;le++){
        float a=s_part[tid][le]+s_part[tid+128][le]+bb;
        s_h1[le][tid]=silu_f(a);
      }
    }
    __syncthreads();
    for (int m=tid;m<1216;m+=256){
      float bb=b2[m];
      float a0=bb,a1=bb,a2=bb,a3=bb;
      for (int o=0;o<128;o++){
        float w=W2[o*1216+m];
        a0+=s_h1[0][o]*w; a1+=s_h1[1][o]*w; a2+=s_h1[2][o]*w; a3+=s_h1[3][o]*w;
      }
      s_h2[0][m]=a0; s_h2[1][m]=a1; s_h2[2][m]=a2; s_h2[3][m]=a3;
    }
    __syncthreads();
    for (int le2=0;le2<ne;le2++){
      int e=s_eix[qb+le2];
      for (int j=tid;j<475;j+=256) s_winv[j]=winv[(size_t)e*475+j];
      __syncthreads();
      const float4* H2=(const float4*)s_h2[le2];
      for (int sI=tid;sI<400;sI+=256){
        int l=sI>>4, c4=sI&15;
        const float* wr=s_winv+l*19;
        float4 acc={0,0,0,0};
        #pragma unroll
        for (int m=0;m<19;m++){
          float w=wr[m];
          float4 hv=H2[m*16+c4];
          acc.x+=w*hv.x; acc.y+=w*hv.y; acc.z+=w*hv.z; acc.w+=w*hv.w;
        }
        float4* A=(float4*)s_acc;
        float4 cur=A[sI];
        cur.x+=acc.x; cur.y+=acc.y; cur.z+=acc.z; cur.w+=acc.w;
        A[sI]=cur;
      }
      __syncthreads();
    }
  }
  int sp=nsp[n];
  for (int j=tid;j<1600;j+=256){
    int l=j>>6, c=j&63;
    float base=(l==0)?spe[sp*64+c]:0.0f;
    x[(size_t)n*1600+j]=base+0.05f*s_acc[j];
  }
}

// ---------------- per-degree RMS norm ----------------
__global__ __launch_bounds__(256) void rmsnorm_kernel(const float* __restrict__ x,
    const float* __restrict__ w, float* __restrict__ xn, int N){
  int n = blockIdx.x, tid = threadIdx.x;
  __shared__ float s_x[1600];
  __shared__ float s_part[256];
  __shared__ float s_ms[64];
  const float* xr = x + (size_t)n*1600;
  for (int j=tid;j<1600;j+=256) s_x[j]=xr[j];
  __syncthreads();
  {
    int c = tid&63, seg = tid>>6;
    float acc=0;
    for (int l=seg;l<25;l+=4){ float v=s_x[l*64+c]; acc+=v*v; }
    s_part[tid]=acc;
  }
  __syncthreads();
  if (tid<64){
    float m=(s_part[tid]+s_part[tid+64]+s_part[tid+128]+s_part[tid+192])*(1.0f/25.0f);
    s_ms[tid]=rsqrtf(m+1e-6f);
  }
  __syncthreads();
  float* xo = xn + (size_t)n*1600;
  for (int j=tid;j<1600;j+=256){
    int l=j>>6, c=j&63;
    xo[j]=s_x[j]*s_ms[c]*w[d_loc[l]*64+c];
  }
}

__global__ __launch_bounds__(256) void init_mxden_kernel(float* mx, float* den, int N){
  int idx = blockIdx.x*256+threadIdx.x;
  if (idx < N*8){ mx[idx]=-3.0e38f; den[idx]=0.0f; }
}

// ---------------- radial MLP (edge-parallel, 4 edges/block) ----------------
__global__ __launch_bounds__(256) void rad_kernel(const float* __restrict__ ev,
    const float* __restrict__ ese, const int* __restrict__ nsp,
    const float* __restrict__ W1, const float* __restrict__ b1,
    const float* __restrict__ W2, const float* __restrict__ b2,
    const int* __restrict__ snd, const int* __restrict__ rcv,
    float* __restrict__ radb, int E){
  int e0 = blockIdx.x*4, tid = threadIdx.x;
  __shared__ float s_ee[4][DIN];
  __shared__ float s_h1[4][128];
  __shared__ float s_part[256][4];
  __shared__ float s_d[4]; __shared__ int s_ss[4]; __shared__ int s_rs[4];
  int ne = E - e0; if (ne > 4) ne = 4;
  if (tid<4){
    int e=e0+tid;
    if (e<E){
      float vx=ev[3*e], vy=ev[3*e+1], vz=ev[3*e+2];
      s_d[tid]=sqrtf(vx*vx+vy*vy+vz*vz+1e-12f);
      s_ss[tid]=nsp[snd[e]]; s_rs[tid]=nsp[rcv[e]];
    } else { s_d[tid]=0.0f; s_ss[tid]=0; s_rs[tid]=0; }
  }
  __syncthreads();
  const float step = 5.0f/599.0f;
  const float inv_std = 1.0f/(2.0f*step);
  for (int j=tid;j<4*DIN;j+=256){
    int le=j/DIN, jj=j%DIN;
    float v;
    if (jj<NRBF){ float t=(s_d[le]-jj*step)*inv_std; v=__expf(-0.5f*t*t); }
    else if (jj<NRBF+64) v=ese[s_ss[le]*128+(jj-NRBF)];
    else v=ese[s_rs[le]*128+64+(jj-NRBF-64)];
    s_ee[le][jj]=v;
  }
  __syncthreads();
  {
    int o=tid&127, half=tid>>7, i0=half*364;
    float a0=0,a1=0,a2=0,a3=0;
    for (int i=i0;i<i0+364;i++){
      float w=W1[i*128+o];
      a0+=s_ee[0][i]*w; a1+=s_ee[1][i]*w; a2+=s_ee[2][i]*w; a3+=s_ee[3][i]*w;
    }
    s_part[tid][0]=a0; s_part[tid][1]=a1; s_part[tid][2]=a2; s_part[tid][3]=a3;
  }
  __syncthreads();
  if (tid<128){
    float bb=b1[tid];
    #pragma unroll
    for (int le=0;le<4;le++){
      float a=s_part[tid][le]+s_part[tid+128][le]+bb;
      s_h1[le][tid]=silu_f(a);
    }
  }
  __syncthreads();
  for (int m=tid;m<384;m+=256){
    float bb=b2[m];
    float a0=bb,a1=bb,a2=bb,a3=bb;
    for (int o=0;o<128;o++){
      float w=W2[o*384+m];
      a0+=s_h1[0][o]*w; a1+=s_h1[1][o]*w; a2+=s_h1[2][o]*w; a3+=s_h1[3][o]*w;
    }
    if (0<ne) radb[(size_t)(e0+0)*384+m]=a0;
    if (1<ne) radb[(size_t)(e0+1)*384+m]=a1;
    if (2<ne) radb[(size_t)(e0+2)*384+m]=a2;
    if (3<ne) radb[(size_t)(e0+3)*384+m]=a3;
  }
}

// ---------------- pass 1: m=0 path -> alpha logits ----------------
__global__ __launch_bounds__(256) void logits_kernel(const float* __restrict__ xn,
    const float* __restrict__ wig, const float* __restrict__ radb,
    const float* __restrict__ so2W, const float* __restrict__ alphaW, const float* __restrict__ alphaV,
    const int* __restrict__ snd, const int* __restrict__ rcv,
    float* __restrict__ logits, float* __restrict__ mx, int E){
  int e = blockIdx.x, tid = threadIdx.x;
  __shared__ float s_cat[3200];
  __shared__ float s_wig0[25];
  __shared__ float s_msg0[128];
  __shared__ float s_sh0[64];
  __shared__ float s_a[256];
  int s = snd[e], r = rcv[e];
  const float4* xs4 = (const float4*)(xn + (size_t)s*1600);
  const float4* xr4 = (const float4*)(xn + (size_t)r*1600);
  float4* cat4 = (float4*)s_cat;
  for (int j=tid;j<400;j+=256){
    int l=j>>4, c4=j&15;
    cat4[l*32+c4]    = xs4[j];
    cat4[l*32+16+c4] = xr4[j];
  }
  if (tid<25) s_wig0[tid]=wig[(size_t)e*475+tid];
  __syncthreads();
  if (tid<128){
    float acc=0;
    #pragma unroll
    for (int l=0;l<25;l++) acc += s_wig0[l]*s_cat[l*128+tid];
    s_msg0[tid]=acc*radb[(size_t)e*384+tid];
  }
  __syncthreads();
  if (tid<64){
    float acc=0;
    #pragma unroll
    for (int k=0;k<128;k++) acc += s_msg0[k]*so2W[k*64+tid];
    s_sh0[tid]=silu_f(acc);
  }
  __syncthreads();
  {
    float acc=0;
    #pragma unroll
    for (int o=0;o<64;o++) acc += s_sh0[o]*alphaW[o*256+tid];
    s_a[tid]=silu_f(acc)*alphaV[tid];
  }
  __syncthreads();
  if (tid<8){
    float lg=0;
    #pragma unroll
    for (int q=0;q<32;q++) lg += s_a[tid*32+q];
    logits[(size_t)e*8+tid]=lg;
    atomicMaxF(&mx[r*8+tid], lg);
  }
}

__global__ __launch_bounds__(256) void den_kernel(const float* __restrict__ logits,
    const float* __restrict__ mx, const int* __restrict__ rcv,
    float* __restrict__ den, int E){
  int idx = blockIdx.x*256+threadIdx.x;
  if (idx >= E*8) return;
  int e = idx>>3, hd = idx&7, r = rcv[e];
  atomicAdd(&den[r*8+hd], __expf(logits[idx]-mx[r*8+hd]));
}

// ---------------- pass 2a: edge-parallel MFMA SO2-conv (4 CSR edges / block) ----------------
// msg rows stacked group-major: 96 rows (6 MFMA row-tiles); swizzled bf16 LDS;
// vv = msg @ wsv_g (MFMA) * attn ; oe = vv @ proj_g (MFMA) -> global bf16 [p][19][64]
__device__ inline void msg_store(unsigned short* smem, int R, int oct, const float* v){
  unsigned u0=((unsigned)f2bf(v[1])<<16)|f2bf(v[0]);
  unsigned u1=((unsigned)f2bf(v[3])<<16)|f2bf(v[2]);
  unsigned u2=((unsigned)f2bf(v[5])<<16)|f2bf(v[4]);
  unsigned u3=((unsigned)f2bf(v[7])<<16)|f2bf(v[6]);
  int4 t; t.x=(int)u0; t.y=(int)u1; t.z=(int)u2; t.w=(int)u3;
  *((int4*)(smem + R*128 + ((oct^(R&7))<<3))) = t;
}

__global__ __launch_bounds__(256) void attn_edge_kernel(const float* __restrict__ xn,
    const float* __restrict__ wig, const float* __restrict__ radb,
    const unsigned short* __restrict__ wsvp, const unsigned short* __restrict__ projp,
    const float* __restrict__ logits, const float* __restrict__ mx, const float* __restrict__ den,
    const int* __restrict__ snd, const int* __restrict__ rcv, const int* __restrict__ eix,
    unsigned short* __restrict__ oe, int E){
  int tid = threadIdx.x;
  int p0 = blockIdx.x*4;
  __shared__ unsigned short s_msg[12288];   // [96][128] bf16, chunk-swizzled
  __shared__ unsigned short s_vv[12288];
  __shared__ float s_cat[3200];
  __shared__ float s_wig[475];
  __shared__ float s_rad[384];
  __shared__ float s_attn[4][8];
  __shared__ int s_r2e[96], s_r2m[96];
  __shared__ int s_e[4], s_s[4], s_r[4];
  int ne = E - p0; if (ne>4) ne=4;
  if (tid<4){
    int ok = (tid<ne);
    int e = ok? eix[p0+tid] : -1;
    s_e[tid]=e;
    s_s[tid]= ok? snd[e] : 0;
    s_r[tid]= ok? rcv[e] : 0;
  }
  { int4 z={0,0,0,0}; for (int j=tid;j<1536;j+=256) ((int4*)s_msg)[j]=z; }
  for (int j=tid;j<96;j+=256){ s_r2e[j]=d_row2e[j]; s_r2m[j]=d_row2m[j]; }
  __syncthreads();
  if (tid<32){
    int i=tid>>3, h=tid&7;
    int e=s_e[i];
    float a=0.0f;
    if (e>=0){
      int r=s_r[i];
      a = __expf(logits[(size_t)e*8+h]-mx[r*8+h])/(den[r*8+h]+1e-12f);
    }
    s_attn[i][h]=a;
  }
  // ---- msg phase: per edge, fp32 rotate * rad -> bf16 swizzled LDS ----
  for (int i=0;i<ne;i++){
    int e=s_e[i], s=s_s[i], r=s_r[i];
    const float4* xs4=(const float4*)(xn+(size_t)s*1600);
    const float4* xr4=(const float4*)(xn+(size_t)r*1600);
    float4* cat4=(float4*)s_cat;
    for (int j=tid;j<400;j+=256){
      int l=j>>4, c4=j&15;
      cat4[l*32+c4]    = xs4[j];
      cat4[l*32+16+c4] = xr4[j];
    }
    for (int j=tid;j<475;j+=256) s_wig[j]=wig[(size_t)e*475+j];
    for (int j=tid;j<96;j+=256) ((float4*)s_rad)[j]=((const float4*)(radb+(size_t)e*384))[j];
    __syncthreads();
    if (tid<160){
      int pr=tid>>4, oct=tid&15;
      int ra=2*pr, rb=ra+1;
      bool hb = (rb<19);
      float a[8], b[8];
      #pragma unroll
      for (int q=0;q<8;q++){ a[q]=0.0f; b[q]=0.0f; }
      const float* wa_=s_wig+ra*25;
      const float* wb_=s_wig+(hb?rb:ra)*25;
      const float4* cp=(const float4*)s_cat;
      #pragma unroll
      for (int l=0;l<25;l++){
        float wa=wa_[l], wb=wb_[l];
        float4 c0=cp[l*32+oct*2], c1=cp[l*32+oct*2+1];
        a[0]+=wa*c0.x; a[1]+=wa*c0.y; a[2]+=wa*c0.z; a[3]+=wa*c0.w;
        a[4]+=wa*c1.x; a[5]+=wa*c1.y; a[6]+=wa*c1.z; a[7]+=wa*c1.w;
        b[0]+=wb*c0.x; b[1]+=wb*c0.y; b[2]+=wb*c0.z; b[3]+=wb*c0.w;
        b[4]+=wb*c1.x; b[5]+=wb*c1.y; b[6]+=wb*c1.z; b[7]+=wb*c1.w;
      }
      const float4* rp=(const float4*)s_rad;
      {
        int g=d_mg[ra];
        float4 r0=rp[g*32+oct*2], r1=rp[g*32+oct*2+1];
        a[0]*=r0.x; a[1]*=r0.y; a[2]*=r0.z; a[3]*=r0.w;
        a[4]*=r1.x; a[5]*=r1.y; a[6]*=r1.z; a[7]*=r1.w;
        int R=d_m2base[ra]+i*d_m2str[ra];
        msg_store(s_msg, R, oct, a);
      }
      if (hb){
        int g=d_mg[rb];
        float4 r0=rp[g*32+oct*2], r1=rp[g*32+oct*2+1];
        b[0]*=r0.x; b[1]*=r0.y; b[2]*=r0.z; b[3]*=r0.w;
        b[4]*=r1.x; b[5]*=r1.y; b[6]*=r1.z; b[7]*=r1.w;
        int R=d_m2base[rb]+i*d_m2str[rb];
        msg_store(s_msg, R, oct, b);
      }
    }
    __syncthreads();
  }
  int wv=tid>>6, lane=tid&63;
  int lanelo=lane&15, khi=lane>>4;
  // ---- vv = msg @ wsv_g (MFMA), *attn, -> bf16 s_vv ----
  {
    int nt0=wv*2, nt1=nt0+1;
    bf16x8 B0[4], B1[4];
    const int4* wp4=(const int4*)wsvp;
    int curg=-1;
    for (int rt=0;rt<6;rt++){
      int g=rt>>1;
      if (g!=curg){
        curg=g;
        #pragma unroll
        for (int kt=0;kt<4;kt++){
          int4 t0=wp4[g*2048+(kt*8+nt0)*64+lane];
          int4 t1=wp4[g*2048+(kt*8+nt1)*64+lane];
          B0[kt]=*(bf16x8*)&t0; B1[kt]=*(bf16x8*)&t1;
        }
      }
      int arow=rt*16+lanelo;
      bf16x8 A[4];
      #pragma unroll
      for (int kt=0;kt<4;kt++){
        int ch=(kt*4+khi)^(arow&7);
        A[kt]=*((const bf16x8*)(s_msg + arow*128 + (ch<<3)));
      }
      f32x4 acc0={0,0,0,0}, acc1={0,0,0,0};
      #pragma unroll
      for (int kt=0;kt<4;kt++){
        acc0=__builtin_amdgcn_mfma_f32_16x16x32_bf16(A[kt],B0[kt],acc0,0,0,0);
        acc1=__builtin_amdgcn_mfma_f32_16x16x32_bf16(A[kt],B1[kt],acc1,0,0,0);
      }
      int rbase=rt*16+khi*4;
      int col0=nt0*16+lanelo, col1=col0+16;
      #pragma unroll
      for (int q=0;q<4;q++){
        int row=rbase+q;
        int ei=s_r2e[row];
        float f0 = (ei>=0)? s_attn[ei][nt0] : 0.0f;
        float f1 = (ei>=0)? s_attn[ei][nt1] : 0.0f;
        s_vv[row*128 + (((col0>>3)^(row&7))<<3) + (col0&7)] = f2bf(acc0[q]*f0);
        s_vv[row*128 + (((col1>>3)^(row&7))<<3) + (col1&7)] = f2bf(acc1[q]*f1);
      }
    }
  }
  __syncthreads();
  // ---- oe = vv @ proj_g (MFMA) -> global bf16 [p][19][64] ----
  {
    int nt=wv;
    bf16x8 P[4];
    const int4* pp4=(const int4*)projp;
    int curg=-1;
    for (int rt=0;rt<6;rt++){
      int g=rt>>1;
      if (g!=curg){
        curg=g;
        #pragma unroll
        for (int kt=0;kt<4;kt++){
          int4 t=pp4[g*1024+(kt*4+nt)*64+lane];
          P[kt]=*(bf16x8*)&t;
        }
      }
      int arow=rt*16+lanelo;
      bf16x8 A[4];
      #pragma unroll
      for (int kt=0;kt<4;kt++){
        int ch=(kt*4+khi)^(arow&7);
        A[kt]=*((const bf16x8*)(s_vv + arow*128 + (ch<<3)));
      }
      f32x4 acc={0,0,0,0};
      #pragma unroll
      for (int kt=0;kt<4;kt++)
        acc=__builtin_amdgcn_mfma_f32_16x16x32_bf16(A[kt],P[kt],acc,0,0,0);
      int rbase=rt*16+khi*4;
      int col=nt*16+lanelo;
      #pragma unroll
      for (int q=0;q<4;q++){
        int row=rbase+q;
        int ei=s_r2e[row];
        if (ei>=0 && s_e[ei]>=0){
          int m=s_r2m[row];
          oe[((size_t)(p0+ei)*19+m)*64+col]=f2bf(acc[q]);
        }
      }
    }
  }
}

// ---------------- pass 2b: per-node gather: winv rotate + accumulate ----------------
__global__ __launch_bounds__(256) void attn_sum_kernel(const unsigned short* __restrict__ oe,
    const float* __restrict__ winv, const int* __restrict__ rowptr, const int* __restrict__ eix,
    float* __restrict__ x, int N){
  int n=blockIdx.x, tid=threadIdx.x;
  __shared__ float s_winv[475];
  __shared__ unsigned short s_oe[1216];   // [19][64] bf16
  int row0=rowptr[n];
  int cnt=rowptr[n+1]-row0;
  float4 acc0={0,0,0,0}, acc1={0,0,0,0};
  int it1=tid+256;
  for (int j=0;j<cnt;j++){
    int p=row0+j;
    int e=eix[p];
    for (int k2=tid;k2<475;k2+=256) s_winv[k2]=winv[(size_t)e*475+k2];
    for (int k2=tid;k2<152;k2+=256) ((int4*)s_oe)[k2]=((const int4*)(oe+(size_t)p*1216))[k2];
    __syncthreads();
    const unsigned* o2=(const unsigned*)s_oe;
    {
      int l=tid>>4, c4=tid&15;
      const float* wr=s_winv+l*19;
      #pragma unroll
      for (int m=0;m<19;m++){
        float w=wr[m];
        unsigned ua=o2[m*32+c4*2], ub=o2[m*32+c4*2+1];
        acc0.x+=w*bf2f((unsigned short)(ua&0xffffu));
        acc0.y+=w*bf2f((unsigned short)(ua>>16));
        acc0.z+=w*bf2f((unsigned short)(ub&0xffffu));
        acc0.w+=w*bf2f((unsigned short)(ub>>16));
      }
    }
    if (it1<400){
      int l=it1>>4, c4=it1&15;
      const float* wr=s_winv+l*19;
      #pragma unroll
      for (int m=0;m<19;m++){
        float w=wr[m];
        unsigned ua=o2[m*32+c4*2], ub=o2[m*32+c4*2+1];
        acc1.x+=w*bf2f((unsigned short)(ua&0xffffu));
        acc1.y+=w*bf2f((unsigned short)(ua>>16));
        acc1.z+=w*bf2f((unsigned short)(ub&0xffffu));
        acc1.w+=w*bf2f((unsigned short)(ub>>16));
      }
    }
    __syncthreads();
  }
  float4* xp=(float4*)(x+(size_t)n*1600);
  {
    float4 c=xp[tid];
    c.x+=acc0.x; c.y+=acc0.y; c.z+=acc0.z; c.w+=acc0.w;
    xp[tid]=c;
  }
  if (it1<400){
    float4 c=xp[it1];
    c.x+=acc1.x; c.y+=acc1.y; c.z+=acc1.z; c.w+=acc1.w;
    xp[it1]=c;
  }
}

// ---------------- S2 grid FFN (W1 staged in LDS) ----------------
__global__ __launch_bounds__(256) void grid_ffn_kernel(const float* __restrict__ xn,
    const float* __restrict__ tg, const float* __restrict__ fg,
    const float* __restrict__ W1, const float* __restrict__ b1, const float* __restrict__ W2,
    float* __restrict__ x, int N){
  int n = blockIdx.x, tid = threadIdx.x;
  __shared__ float s_xn[1600];
  __shared__ float s_W1[8192];
  __shared__ float s_W2[8192];
  __shared__ float s_b1[128];
  __shared__ float s_g[4][64];
  __shared__ float s_hid[4][128];
  __shared__ float s_o[4][64];
  const float* xr = xn + (size_t)n*1600;
  for (int j=tid;j<1600;j+=256) s_xn[j]=xr[j];
  {
    const float4* src1=(const float4*)W1;
    const float4* src2=(const float4*)W2;
    float4* dst1=(float4*)s_W1;
    float4* dst2=(float4*)s_W2;
    for (int j=tid;j<2048;j+=256){ dst1[j]=src1[j]; dst2[j]=src2[j]; }
  }
  if (tid<128) s_b1[tid]=b1[tid];
  float accv[7];
  #pragma unroll
  for (int t=0;t<7;t++) accv[t]=0.0f;
  __syncthreads();
  for (int gp=0; gp<GPTS; gp+=4){
    int gpl=tid>>6, c=tid&63;
    {
      float a=0;
      #pragma unroll
      for (int l=0;l<25;l++) a += tg[(gp+gpl)*25+l]*s_xn[l*64+c];
      s_g[gpl][c]=a;
    }
    __syncthreads();
    {
      int hh=tid&127, gh=tid>>7;
      #pragma unroll
      for (int q=0;q<2;q++){
        int gg=gh+2*q;
        float h=s_b1[hh];
        #pragma unroll
        for (int cc=0;cc<64;cc++) h += s_g[gg][cc]*s_W1[cc*128+hh];
        s_hid[gg][hh]=silu_f(h);
      }
    }
    __syncthreads();
    {
      float o=0;
      #pragma unroll
      for (int hh=0;hh<128;hh++) o += s_hid[gpl][hh]*s_W2[hh*64+c];
      s_o[gpl][c]=o;
    }
    __syncthreads();
    {
      int t=0;
      for (int idx=tid; idx<1600; idx+=256, t++){
        int l=idx>>6, cc=idx&63;
        float s=0;
        #pragma unroll
        for (int g2=0; g2<4; g2++) s += fg[l*288+gp+g2]*s_o[g2][cc];
        accv[t]+=s;
      }
    }
    __syncthreads();
  }
  {
    int t=0;
    for (int idx=tid; idx<1600; idx+=256, t++) x[(size_t)n*1600+idx] += accv[t];
  }
}

// ---------------- final energy head ----------------
__global__ __launch_bounds__(256) void energy_kernel(const float* __restrict__ xn,
    const float* __restrict__ tg, const float* __restrict__ fg,
    const float* __restrict__ W1, const float* __restrict__ b1,
    const float* __restrict__ W2, const float* __restrict__ b2,
    float* __restrict__ out, int N){
  int n = blockIdx.x, tid = threadIdx.x;
  __shared__ float s_xn[1600];
  __shared__ float s_W1[8192];
  __shared__ float s_b1[128];
  __shared__ float s_w2[128];
  __shared__ float s_g[4][64];
  __shared__ float s_hid[4][128];
  __shared__ float s_red[4][64];
  const float* xr = xn + (size_t)n*1600;
  for (int j=tid;j<1600;j+=256) s_xn[j]=xr[j];
  {
    const float4* src=(const float4*)W1;
    float4* dst=(float4*)s_W1;
    for (int j=tid;j<2048;j+=256) dst[j]=src[j];
  }
  if (tid<128){ s_b1[tid]=b1[tid]; s_w2[tid]=W2[tid]; }
  float b2v = b2[0];
  float priv = 0.0f;
  __syncthreads();
  for (int gp=0; gp<GPTS; gp+=4){
    int gpl=tid>>6, c=tid&63;
    {
      float a=0;
      #pragma unroll
      for (int l=0;l<25;l++) a += tg[(gp+gpl)*25+l]*s_xn[l*64+c];
      s_g[gpl][c]=a;
    }
    __syncthreads();
    {
      int hh=tid&127, gh=tid>>7;
      #pragma unroll
      for (int q=0;q<2;q++){
        int gg=gh+2*q;
        float h=s_b1[hh];
        #pragma unroll
        for (int cc=0;cc<64;cc++) h += s_g[gg][cc]*s_W1[cc*128+hh];
        s_hid[gg][hh]=silu_f(h);
      }
    }
    __syncthreads();
    {
      float part = s_hid[gpl][c]*s_w2[c] + s_hid[gpl][c+64]*s_w2[c+64];
      s_red[gpl][c]=part;
    }
    __syncthreads();
    if (tid<4){
      float sum=0;
      #pragma unroll
      for (int q=0;q<64;q++) sum += s_red[tid][q];
      priv += fg[gp+tid]*(sum+b2v);
    }
    __syncthreads();
  }
  if (tid<4) s_red[0][tid]=priv;
  __syncthreads();
  if (tid==0) out[n]=(s_red[0][0]+s_red[0][1]+s_red[0][2]+s_red[0][3])*(1.0f/2000.0f);
}

extern "C" void kernel_launch(void* const* d_in, const int* in_sizes, int n_in,
                              void* d_out, int out_size, void* d_ws, size_t ws_size,
                              hipStream_t stream){
  (void)n_in; (void)out_size; (void)ws_size;
  const float* ev   = (const float*)d_in[0];
  const float* wig  = (const float*)d_in[1];
  const float* winv = (const float*)d_in[2];
  const float* spe  = (const float*)d_in[3];
  const float* ese  = (const float*)d_in[4];
  const float* degW1= (const float*)d_in[5];
  const float* degb1= (const float*)d_in[6];
  const float* degW2= (const float*)d_in[7];
  const float* degb2= (const float*)d_in[8];
  const float* n1w  = (const float*)d_in[9];
  const float* radW1= (const float*)d_in[10];
  const float* radb1= (const float*)d_in[11];
  const float* radW2= (const float*)d_in[12];
  const float* radb2= (const float*)d_in[13];
  const float* so2W = (const float*)d_in[14];
  const float* aW   = (const float*)d_in[15];
  const float* aV   = (const float*)d_in[16];
  const float* vW   = (const float*)d_in[17];
  const float* pW   = (const float*)d_in[18];
  const float* n2w  = (const float*)d_in[19];
  const float* fW1  = (const float*)d_in[20];
  const float* fb1  = (const float*)d_in[21];
  const float* fW2  = (const float*)d_in[22];
  const float* tg   = (const float*)d_in[23];
  const float* fg   = (const float*)d_in[24];
  const float* fnw  = (const float*)d_in[25];
  const float* enW1 = (const float*)d_in[26];
  const float* enb1 = (const float*)d_in[27];
  const float* enW2 = (const float*)d_in[28];
  const float* enb2 = (const float*)d_in[29];
  const int* nsp = (const int*)d_in[30];
  const int* snd = (const int*)d_in[31];
  const int* rcv = (const int*)d_in[32];
  int N = in_sizes[30];
  int E = in_sizes[31];
  float* out = (float*)d_out;

  float* ws = (float*)d_ws;
  size_t off = 0;
  float* radbuf = ws + off; off += (size_t)E*384;
  float* logits = ws + off; off += (size_t)E*8;
  float* mx     = ws + off; off += (size_t)N*8;
  float* den    = ws + off; off += (size_t)N*8;
  float* x      = ws + off; off += (size_t)N*1600;
  float* xn     = ws + off; off += (size_t)N*1600;
  unsigned short* wsvb  = (unsigned short*)(ws + off); off += (size_t)6*16384/2;
  unsigned short* projb = (unsigned short*)(ws + off); off += (size_t)6*8192/2;
  int* cnt      = (int*)(ws + off); off += (size_t)N;
  int* rowptr   = (int*)(ws + off); off += (size_t)(N+1);
  int* fill     = (int*)(ws + off); off += (size_t)N;
  int* eixbuf   = (int*)(ws + off); off += (size_t)E;
  off = (off + 3) & ~((size_t)3);                       // 16B-align oe buffer
  unsigned short* oebuf = (unsigned short*)(ws + off); off += (size_t)E*608;  // [E][19][64] bf16

  // CSR by receiver + bf16 fused weights (fragment-packed for MFMA B-operand)
  zero_cnt_kernel<<<(N+255)/256, 256, 0, stream>>>(cnt, N);
  csr_count_kernel<<<(E+255)/256, 256, 0, stream>>>(rcv, cnt, E);
  csr_scan_kernel<<<1, 256, 0, stream>>>(cnt, rowptr, fill, N);
  csr_fill_kernel<<<(E+255)/256, 256, 0, stream>>>(rcv, fill, eixbuf, E);
  wsvb_kernel<<<6, 256, 0, stream>>>(so2W, vW, wsvb);
  projb_kernel<<<6, 256, 0, stream>>>(pW, projb);

  deg_gather_kernel<<<N, 256, 0, stream>>>(ev, ese, nsp, spe, degW1, degb1, degW2, degb2,
                                           winv, snd, rowptr, eixbuf, x, N);

  for (int i=0;i<2;i++){
    rmsnorm_kernel<<<N, 256, 0, stream>>>(x, n1w + (size_t)i*320, xn, N);
    init_mxden_kernel<<<(N*8+255)/256, 256, 0, stream>>>(mx, den, N);
    rad_kernel<<<(E+3)/4, 256, 0, stream>>>(ev, ese, nsp, radW1 + (size_t)i*DIN*128, radb1 + (size_t)i*128,
                                            radW2 + (size_t)i*128*384, radb2 + (size_t)i*384,
                                            snd, rcv, radbuf, E);
    logits_kernel<<<E, 256, 0, stream>>>(xn, wig, radbuf, so2W + (size_t)i*24576,
                                         aW + (size_t)i*64*256, aV + (size_t)i*256,
                                         snd, rcv, logits, mx, E);
    den_kernel<<<(E*8+255)/256, 256, 0, stream>>>(logits, mx, rcv, den, E);
    attn_edge_kernel<<<(E+3)/4, 256, 0, stream>>>(xn, wig, radbuf,
                                                  wsvb + (size_t)i*3*16384, projb + (size_t)i*3*8192,
                                                  logits, mx, den, snd, rcv, eixbuf, oebuf, E);
    attn_sum_kernel<<<N, 256, 0, stream>>>(oebuf, winv, rowptr, eixbuf, x, N);
    rmsnorm_kernel<<<N, 256, 0, stream>>>(x, n2w + (size_t)i*320, xn, N);
    grid_ffn_kernel<<<N, 256, 0, stream>>>(xn, tg, fg, fW1 + (size_t)i*8192, fb1 + (size_t)i*128,
                                           fW2 + (size_t)i*8192, x, N);
  }
  rmsnorm_kernel<<<N, 256, 0, stream>>>(x, fnw, xn, N);
  energy_kernel<<<N, 256, 0, stream>>>(xn, tg, fg, enW1, enb1, enW2, enb2, out, N);
}

// Round 3
// 5030.857 us; speedup vs baseline: 1.6770x; 1.4530x over previous
//
#include <hip/hip_runtime.h>
#include <hip/hip_bf16.h>
#include <math.h>

// EquiformerV2 block, fp32 activations. Round 9: grid FFN + energy head on MFMA with
// split-bf16 (hi/lo, 3-term) GEMMs for fp32-grade accuracy; fixed oebuf allocation
// (E*608 floats, was halved in round 8). Attention SO2-conv GEMMs on MFMA (round 7).
// E=40000 edges, N=2000 nodes, C=64, L2=25, M2=19, NL=2.

#define NRBF 600
#define DIN 728
#define GPTS 288
#define MAXE 160

typedef __attribute__((ext_vector_type(8))) short bf16x8;
typedef __attribute__((ext_vector_type(4))) float f32x4;

__constant__ int d_mg[19] = {0,1,0,1,2,1,0,1,2,2,1,0,1,2,2,1,0,1,2};
__constant__ int d_loc[25] = {0,1,1,1,2,2,2,2,2,3,3,3,3,3,3,3,4,4,4,4,4,4,4,4,4};
// EB=4 group-major row layout: g0 rows 0..19 (pad to 32), g1 rows 32..63, g2 rows 64..87 (pad to 96)
__constant__ int d_row2e[96] = {
  0,0,0,0,0, 1,1,1,1,1, 2,2,2,2,2, 3,3,3,3,3, -1,-1,-1,-1,-1,-1,-1,-1,-1,-1,-1,-1,
  0,0,0,0,0,0,0,0, 1,1,1,1,1,1,1,1, 2,2,2,2,2,2,2,2, 3,3,3,3,3,3,3,3,
  0,0,0,0,0,0, 1,1,1,1,1,1, 2,2,2,2,2,2, 3,3,3,3,3,3, -1,-1,-1,-1,-1,-1,-1,-1};
__constant__ int d_row2m[96] = {
  0,2,6,11,16, 0,2,6,11,16, 0,2,6,11,16, 0,2,6,11,16, 0,0,0,0,0,0,0,0,0,0,0,0,
  1,3,5,7,10,12,15,17, 1,3,5,7,10,12,15,17, 1,3,5,7,10,12,15,17, 1,3,5,7,10,12,15,17,
  4,8,9,13,14,18, 4,8,9,13,14,18, 4,8,9,13,14,18, 4,8,9,13,14,18, 0,0,0,0,0,0,0,0};
// m -> (row base, per-edge stride) in the 96-row layout
__constant__ int d_m2base[19] = {0,32,1,33,64,34,2,35,65,66,36,3,37,67,68,38,4,39,69};
__constant__ int d_m2str[19]  = {5,8,5,8,6,8,5,8,6,6,8,5,8,6,6,8,5,8,6};

__device__ inline float silu_f(float v){ return v/(1.0f+__expf(-v)); }
__device__ inline float bf2f(unsigned short u){ return __uint_as_float(((unsigned)u)<<16); }
__device__ inline unsigned short f2bf(float f){
  unsigned b=__float_as_uint(f);
  return (unsigned short)((b + 0x7FFF + ((b>>16)&1)) >> 16);
}

__device__ inline void atomicMaxF(float* addr, float val){
  int* ia=(int*)addr;
  int old=*ia;
  while (__int_as_float(old) < val){
    int assumed=old;
    old = atomicCAS(ia, assumed, __float_as_int(val));
    if (old == assumed) break;
  }
}

// ---------------- CSR build ----------------
__global__ __launch_bounds__(256) void zero_cnt_kernel(int* cnt, int N){
  int i = blockIdx.x*256+threadIdx.x;
  if (i<N) cnt[i]=0;
}
__global__ __launch_bounds__(256) void csr_count_kernel(const int* __restrict__ rcv, int* cnt, int E){
  int i = blockIdx.x*256+threadIdx.x;
  if (i<E) atomicAdd(&cnt[rcv[i]],1);
}
__global__ __launch_bounds__(256) void csr_scan_kernel(const int* __restrict__ cnt,
    int* rowptr, int* fill, int N){
  __shared__ int s_part[256];
  int tid=threadIdx.x;
  int chunk=(N+255)/256;
  int lvals[12];
  int base=tid*chunk;
  int lsum=0;
  for (int i=0;i<chunk && i<12;i++){
    int v=(base+i<N)?cnt[base+i]:0;
    lvals[i]=lsum; lsum+=v;
  }
  s_part[tid]=lsum;
  __syncthreads();
  if (tid==0){
    int run=0;
    for (int t=0;t<256;t++){ int v=s_part[t]; s_part[t]=run; run+=v; }
  }
  __syncthreads();
  int off=s_part[tid];
  for (int i=0;i<chunk && i<12;i++){
    if (base+i<N){ rowptr[base+i]=off+lvals[i]; fill[base+i]=off+lvals[i]; }
  }
  if (tid==255) rowptr[N]=off+lsum;
}
__global__ __launch_bounds__(256) void csr_fill_kernel(const int* __restrict__ rcv,
    int* fill, int* eix, int E){
  int i = blockIdx.x*256+threadIdx.x;
  if (i<E){ int p=atomicAdd(&fill[rcv[i]],1); eix[p]=i; }
}

// ---------------- fused so2W@valW -> bf16 wsvb, MFMA-B-fragment packed ----------------
// frag layout: idx = ((kt*8+nt)*64 + lane)*8 + i ; k = kt*32 + (lane>>4)*8 + i ; col = nt*16 + (lane&15)
__global__ __launch_bounds__(256) void wsvb_kernel(const float* __restrict__ so2W,
    const float* __restrict__ valW, unsigned short* __restrict__ wsvb){
  int i=blockIdx.x/3, g=blockIdx.x%3;
  const float* A = so2W + (size_t)i*24576 + g*8192;   // [128][64]
  const float* B = valW + (size_t)i*24576 + g*8192;   // [64][128]
  unsigned short* C = wsvb + (size_t)blockIdx.x*16384;
  __shared__ float sB[8192];
  for (int j=threadIdx.x;j<2048;j+=256) ((float4*)sB)[j]=((const float4*)B)[j];
  __syncthreads();
  for (int idx=threadIdx.x; idx<16384; idx+=256){
    int k=idx>>7, j=idx&127;
    float acc=0;
    #pragma unroll 4
    for (int o=0;o<64;o++) acc += A[k*64+o]*sB[o*128+j];
    int pos = ((k>>5)*8 + (j>>4))*512 + (((k>>3)&3)*16 + (j&15))*8 + (k&7);
    C[pos]=f2bf(acc);
  }
}

// ---------------- projW -> bf16 [6][128][64], MFMA-B-fragment packed ----------------
__global__ __launch_bounds__(256) void projb_kernel(const float* __restrict__ pW,
    unsigned short* __restrict__ projb){
  const float* src = pW + (size_t)blockIdx.x*8192;
  unsigned short* dst = projb + (size_t)blockIdx.x*8192;
  for (int idx=threadIdx.x; idx<8192; idx+=256){
    int k=idx>>6, j=idx&63;
    int pos = ((k>>5)*4 + (j>>4))*512 + (((k>>3)&3)*16 + (j&15))*8 + (k&7);
    dst[pos]=f2bf(src[idx]);
  }
}

// ---------------- generic B-fragment packer, hi/lo split: src [K][Nn] fp32 ----------------
__global__ __launch_bounds__(256) void packB2_kernel(const float* __restrict__ src,
    unsigned short* __restrict__ dh, unsigned short* __restrict__ dl, int K, int Nn){
  int tid=threadIdx.x;
  int nnt=Nn>>4;
  int tot=K*Nn;
  for (int idx=tid; idx<tot; idx+=256){
    int f=idx>>9, r=idx&511, lane=r>>3, j=r&7;
    int kt=f/nnt, nt=f-kt*nnt;
    int k=kt*32+(lane>>4)*8+j, c=nt*16+(lane&15);
    float v=src[k*Nn+c];
    unsigned short h=f2bf(v);
    dh[idx]=h;
    dl[idx]=f2bf(v-bf2f(h));
  }
}

// ---------------- tg [288][25] -> A-frags per 16-row tile (K=32 pad), hi/lo ----------------
__global__ __launch_bounds__(256) void pack_tg2_kernel(const float* __restrict__ tg,
    unsigned short* __restrict__ tgp){   // hi [0..9216) | lo [9216..18432)
  int tid=threadIdx.x;
  for (int idx=tid; idx<9216; idx+=256){
    int t=idx>>9, r=idx&511, lane=r>>3, j=r&7;
    int kl=(lane>>4)*8+j, row=t*16+(lane&15);
    float v=(kl<25)? tg[row*25+kl] : 0.0f;
    unsigned short h=f2bf(v);
    tgp[idx]=h;
    tgp[9216+idx]=f2bf(v-bf2f(h));
  }
}

// ---------------- fg [25][288] -> A-frags [t][mt] (M pad 32, K=16 valid of 32), hi/lo ----------------
__global__ __launch_bounds__(256) void pack_fg2_kernel(const float* __restrict__ fg,
    unsigned short* __restrict__ fgp){   // hi [0..18432) | lo [18432..36864)
  int tid=threadIdx.x;
  for (int idx=tid; idx<18432; idx+=256){
    int f=idx>>9, r=idx&511, lane=r>>3, j=r&7;
    int t=f>>1, mt=f&1;
    int row=mt*16+(lane&15), k=(lane>>4)*8+j;
    float v=(row<25 && k<16)? fg[row*288+t*16+k] : 0.0f;
    unsigned short h=f2bf(v);
    fgp[idx]=h;
    fgp[18432+idx]=f2bf(v-bf2f(h));
  }
}

// ---------------- edge degree embedding, gather form (per node) ----------------
__global__ __launch_bounds__(256) void deg_gather_kernel(const float* __restrict__ ev,
    const float* __restrict__ ese, const int* __restrict__ nsp, const float* __restrict__ spe,
    const float* __restrict__ W1, const float* __restrict__ b1,
    const float* __restrict__ W2, const float* __restrict__ b2,
    const float* __restrict__ winv, const int* __restrict__ snd,
    const int* __restrict__ rowptr, const int* __restrict__ eix,
    float* __restrict__ x, int N){
  int n = blockIdx.x, tid = threadIdx.x;
  __shared__ float s_ee[4][DIN];
  __shared__ float s_h1[4][128];
  __shared__ float s_h2[4][1216];
  __shared__ float s_part[256][4];
  __shared__ float s_acc[1600];
  __shared__ float s_winv[475];
  __shared__ int s_eix[MAXE];
  __shared__ float s_d[4]; __shared__ int s_ss[4]; __shared__ int s_rs[4];
  int row0=rowptr[n];
  int cnt=rowptr[n+1]-row0; if (cnt>MAXE) cnt=MAXE;
  {
    float4 z={0,0,0,0};
    for (int j=tid;j<400;j+=256) ((float4*)s_acc)[j]=z;
    for (int j=tid;j<cnt;j+=256) s_eix[j]=eix[row0+j];
  }
  __syncthreads();
  int nq=(cnt+3)>>2;
  for (int q=0;q<nq;q++){
    int qb=q*4;
    int ne=cnt-qb; if (ne>4) ne=4;
    if (tid<4){
      int le=qb+tid;
      if (le<cnt){
        int e=s_eix[le];
        float vx=ev[3*e], vy=ev[3*e+1], vz=ev[3*e+2];
        s_d[tid]=sqrtf(vx*vx+vy*vy+vz*vz+1e-12f);
        s_ss[tid]=nsp[snd[e]];
        s_rs[tid]=nsp[n];
      } else { s_d[tid]=0.0f; s_ss[tid]=0; s_rs[tid]=0; }
    }
    __syncthreads();
    const float step = 5.0f/599.0f;
    const float inv_std = 1.0f/(2.0f*step);
    for (int j=tid;j<4*DIN;j+=256){
      int le=j/DIN, jj=j%DIN;
      float v;
      if (jj<NRBF){ float t=(s_d[le]-jj*step)*inv_std; v=__expf(-0.5f*t*t); }
      else if (jj<NRBF+64) v=ese[s_ss[le]*128+(jj-NRBF)];
      else v=ese[s_rs[le]*128+64+(jj-NRBF-64)];
      s_ee[le][jj]=v;
    }
    __syncthreads();
    {
      int o=tid&127, half=tid>>7, i0=half*364;
      float a0=0,a1=0,a2=0,a3=0;
      for (int i=i0;i<i0+364;i++){
        float w=W1[i*128+o];
        a0+=s_ee[0][i]*w; a1+=s_ee[1][i]*w; a2+=s_ee[2][i]*w; a3+=s_ee[3][i]*w;
      }
      s_part[tid][0]=a0; s_part[tid][1]=a1; s_part[tid][2]=a2; s_part[tid][3]=a3;
    }
    __syncthreads();
    if (tid<128){
      float bb=b1[tid];
      #pragma unroll
      for (int le=0;le<4;le++){
        float a=s_part[tid][le]+s_part[tid+128][le]+bb;
        s_h1[le][tid]=silu_f(a);
      }
    }
    __syncthreads();
    for (int m=tid;m<1216;m+=256){
      float bb=b2[m];
      float a0=bb,a1=bb,a2=bb,a3=bb;
      for (int o=0;o<128;o++){
        float w=W2[o*1216+m];
        a0+=s_h1[0][o]*w; a1+=s_h1[1][o]*w; a2+=s_h1[2][o]*w; a3+=s_h1[3][o]*w;
      }
      s_h2[0][m]=a0; s_h2[1][m]=a1; s_h2[2][m]=a2; s_h2[3][m]=a3;
    }
    __syncthreads();
    for (int le2=0;le2<ne;le2++){
      int e=s_eix[qb+le2];
      for (int j=tid;j<475;j+=256) s_winv[j]=winv[(size_t)e*475+j];
      __syncthreads();
      const float4* H2=(const float4*)s_h2[le2];
      for (int sI=tid;sI<400;sI+=256){
        int l=sI>>4, c4=sI&15;
        const float* wr=s_winv+l*19;
        float4 acc={0,0,0,0};
        #pragma unroll
        for (int m=0;m<19;m++){
          float w=wr[m];
          float4 hv=H2[m*16+c4];
          acc.x+=w*hv.x; acc.y+=w*hv.y; acc.z+=w*hv.z; acc.w+=w*hv.w;
        }
        float4* A=(float4*)s_acc;
        float4 cur=A[sI];
        cur.x+=acc.x; cur.y+=acc.y; cur.z+=acc.z; cur.w+=acc.w;
        A[sI]=cur;
      }
      __syncthreads();
    }
  }
  int sp=nsp[n];
  for (int j=tid;j<1600;j+=256){
    int l=j>>6, c=j&63;
    float base=(l==0)?spe[sp*64+c]:0.0f;
    x[(size_t)n*1600+j]=base+0.05f*s_acc[j];
  }
}

// ---------------- per-degree RMS norm ----------------
__global__ __launch_bounds__(256) void rmsnorm_kernel(const float* __restrict__ x,
    const float* __restrict__ w, float* __restrict__ xn, int N){
  int n = blockIdx.x, tid = threadIdx.x;
  __shared__ float s_x[1600];
  __shared__ float s_part[256];
  __shared__ float s_ms[64];
  const float* xr = x + (size_t)n*1600;
  for (int j=tid;j<1600;j+=256) s_x[j]=xr[j];
  __syncthreads();
  {
    int c = tid&63, seg = tid>>6;
    float acc=0;
    for (int l=seg;l<25;l+=4){ float v=s_x[l*64+c]; acc+=v*v; }
    s_part[tid]=acc;
  }
  __syncthreads();
  if (tid<64){
    float m=(s_part[tid]+s_part[tid+64]+s_part[tid+128]+s_part[tid+192])*(1.0f/25.0f);
    s_ms[tid]=rsqrtf(m+1e-6f);
  }
  __syncthreads();
  float* xo = xn + (size_t)n*1600;
  for (int j=tid;j<1600;j+=256){
    int l=j>>6, c=j&63;
    xo[j]=s_x[j]*s_ms[c]*w[d_loc[l]*64+c];
  }
}

__global__ __launch_bounds__(256) void init_mxden_kernel(float* mx, float* den, int N){
  int idx = blockIdx.x*256+threadIdx.x;
  if (idx < N*8){ mx[idx]=-3.0e38f; den[idx]=0.0f; }
}

// ---------------- radial MLP (edge-parallel, 4 edges/block) ----------------
__global__ __launch_bounds__(256) void rad_kernel(const float* __restrict__ ev,
    const float* __restrict__ ese, const int* __restrict__ nsp,
    const float* __restrict__ W1, const float* __restrict__ b1,
    const float* __restrict__ W2, const float* __restrict__ b2,
    const int* __restrict__ snd, const int* __restrict__ rcv,
    float* __restrict__ radb, int E){
  int e0 = blockIdx.x*4, tid = threadIdx.x;
  __shared__ float s_ee[4][DIN];
  __shared__ float s_h1[4][128];
  __shared__ float s_part[256][4];
  __shared__ float s_d[4]; __shared__ int s_ss[4]; __shared__ int s_rs[4];
  int ne = E - e0; if (ne > 4) ne = 4;
  if (tid<4){
    int e=e0+tid;
    if (e<E){
      float vx=ev[3*e], vy=ev[3*e+1], vz=ev[3*e+2];
      s_d[tid]=sqrtf(vx*vx+vy*vy+vz*vz+1e-12f);
      s_ss[tid]=nsp[snd[e]]; s_rs[tid]=nsp[rcv[e]];
    } else { s_d[tid]=0.0f; s_ss[tid]=0; s_rs[tid]=0; }
  }
  __syncthreads();
  const float step = 5.0f/599.0f;
  const float inv_std = 1.0f/(2.0f*step);
  for (int j=tid;j<4*DIN;j+=256){
    int le=j/DIN, jj=j%DIN;
    float v;
    if (jj<NRBF){ float t=(s_d[le]-jj*step)*inv_std; v=__expf(-0.5f*t*t); }
    else if (jj<NRBF+64) v=ese[s_ss[le]*128+(jj-NRBF)];
    else v=ese[s_rs[le]*128+64+(jj-NRBF-64)];
    s_ee[le][jj]=v;
  }
  __syncthreads();
  {
    int o=tid&127, half=tid>>7, i0=half*364;
    float a0=0,a1=0,a2=0,a3=0;
    for (int i=i0;i<i0+364;i++){
      float w=W1[i*128+o];
      a0+=s_ee[0][i]*w; a1+=s_ee[1][i]*w; a2+=s_ee[2][i]*w; a3+=s_ee[3][i]*w;
    }
    s_part[tid][0]=a0; s_part[tid][1]=a1; s_part[tid][2]=a2; s_part[tid][3]=a3;
  }
  __syncthreads();
  if (tid<128){
    float bb=b1[tid];
    #pragma unroll
    for (int le=0;le<4;le++){
      float a=s_part[tid][le]+s_part[tid+128][le]+bb;
      s_h1[le][tid]=silu_f(a);
    }
  }
  __syncthreads();
  for (int m=tid;m<384;m+=256){
    float bb=b2[m];
    float a0=bb,a1=bb,a2=bb,a3=bb;
    for (int o=0;o<128;o++){
      float w=W2[o*384+m];
      a0+=s_h1[0][o]*w; a1+=s_h1[1][o]*w; a2+=s_h1[2][o]*w; a3+=s_h1[3][o]*w;
    }
    if (0<ne) radb[(size_t)(e0+0)*384+m]=a0;
    if (1<ne) radb[(size_t)(e0+1)*384+m]=a1;
    if (2<ne) radb[(size_t)(e0+2)*384+m]=a2;
    if (3<ne) radb[(size_t)(e0+3)*384+m]=a3;
  }
}

// ---------------- pass 1: m=0 path -> alpha logits ----------------
__global__ __launch_bounds__(256) void logits_kernel(const float* __restrict__ xn,
    const float* __restrict__ wig, const float* __restrict__ radb,
    const float* __restrict__ so2W, const float* __restrict__ alphaW, const float* __restrict__ alphaV,
    const int* __restrict__ snd, const int* __restrict__ rcv,
    float* __restrict__ logits, float* __restrict__ mx, int E){
  int e = blockIdx.x, tid = threadIdx.x;
  __shared__ float s_cat[3200];
  __shared__ float s_wig0[25];
  __shared__ float s_msg0[128];
  __shared__ float s_sh0[64];
  __shared__ float s_a[256];
  int s = snd[e], r = rcv[e];
  const float4* xs4 = (const float4*)(xn + (size_t)s*1600);
  const float4* xr4 = (const float4*)(xn + (size_t)r*1600);
  float4* cat4 = (float4*)s_cat;
  for (int j=tid;j<400;j+=256){
    int l=j>>4, c4=j&15;
    cat4[l*32+c4]    = xs4[j];
    cat4[l*32+16+c4] = xr4[j];
  }
  if (tid<25) s_wig0[tid]=wig[(size_t)e*475+tid];
  __syncthreads();
  if (tid<128){
    float acc=0;
    #pragma unroll
    for (int l=0;l<25;l++) acc += s_wig0[l]*s_cat[l*128+tid];
    s_msg0[tid]=acc*radb[(size_t)e*384+tid];
  }
  __syncthreads();
  if (tid<64){
    float acc=0;
    #pragma unroll
    for (int k=0;k<128;k++) acc += s_msg0[k]*so2W[k*64+tid];
    s_sh0[tid]=silu_f(acc);
  }
  __syncthreads();
  {
    float acc=0;
    #pragma unroll
    for (int o=0;o<64;o++) acc += s_sh0[o]*alphaW[o*256+tid];
    s_a[tid]=silu_f(acc)*alphaV[tid];
  }
  __syncthreads();
  if (tid<8){
    float lg=0;
    #pragma unroll
    for (int q=0;q<32;q++) lg += s_a[tid*32+q];
    logits[(size_t)e*8+tid]=lg;
    atomicMaxF(&mx[r*8+tid], lg);
  }
}

__global__ __launch_bounds__(256) void den_kernel(const float* __restrict__ logits,
    const float* __restrict__ mx, const int* __restrict__ rcv,
    float* __restrict__ den, int E){
  int idx = blockIdx.x*256+threadIdx.x;
  if (idx >= E*8) return;
  int e = idx>>3, hd = idx&7, r = rcv[e];
  atomicAdd(&den[r*8+hd], __expf(logits[idx]-mx[r*8+hd]));
}

// ---------------- pass 2a: edge-parallel MFMA SO2-conv (4 CSR edges / block) ----------------
__device__ inline void msg_store(unsigned short* smem, int R, int oct, const float* v){
  unsigned u0=((unsigned)f2bf(v[1])<<16)|f2bf(v[0]);
  unsigned u1=((unsigned)f2bf(v[3])<<16)|f2bf(v[2]);
  unsigned u2=((unsigned)f2bf(v[5])<<16)|f2bf(v[4]);
  unsigned u3=((unsigned)f2bf(v[7])<<16)|f2bf(v[6]);
  int4 t; t.x=(int)u0; t.y=(int)u1; t.z=(int)u2; t.w=(int)u3;
  *((int4*)(smem + R*128 + ((oct^(R&7))<<3))) = t;
}

__global__ __launch_bounds__(256) void attn_edge_kernel(const float* __restrict__ xn,
    const float* __restrict__ wig, const float* __restrict__ radb,
    const unsigned short* __restrict__ wsvp, const unsigned short* __restrict__ projp,
    const float* __restrict__ logits, const float* __restrict__ mx, const float* __restrict__ den,
    const int* __restrict__ snd, const int* __restrict__ rcv, const int* __restrict__ eix,
    unsigned short* __restrict__ oe, int E){
  int tid = threadIdx.x;
  int p0 = blockIdx.x*4;
  __shared__ unsigned short s_msg[12288];   // [96][128] bf16, chunk-swizzled
  __shared__ unsigned short s_vv[12288];
  __shared__ float s_cat[3200];
  __shared__ float s_wig[475];
  __shared__ float s_rad[384];
  __shared__ float s_attn[4][8];
  __shared__ int s_r2e[96], s_r2m[96];
  __shared__ int s_e[4], s_s[4], s_r[4];
  int ne = E - p0; if (ne>4) ne=4;
  if (tid<4){
    int ok = (tid<ne);
    int e = ok? eix[p0+tid] : -1;
    s_e[tid]=e;
    s_s[tid]= ok? snd[e] : 0;
    s_r[tid]= ok? rcv[e] : 0;
  }
  { int4 z={0,0,0,0}; for (int j=tid;j<1536;j+=256) ((int4*)s_msg)[j]=z; }
  for (int j=tid;j<96;j+=256){ s_r2e[j]=d_row2e[j]; s_r2m[j]=d_row2m[j]; }
  __syncthreads();
  if (tid<32){
    int i=tid>>3, h=tid&7;
    int e=s_e[i];
    float a=0.0f;
    if (e>=0){
      int r=s_r[i];
      a = __expf(logits[(size_t)e*8+h]-mx[r*8+h])/(den[r*8+h]+1e-12f);
    }
    s_attn[i][h]=a;
  }
  // ---- msg phase: per edge, fp32 rotate * rad -> bf16 swizzled LDS ----
  for (int i=0;i<ne;i++){
    int e=s_e[i], s=s_s[i], r=s_r[i];
    const float4* xs4=(const float4*)(xn+(size_t)s*1600);
    const float4* xr4=(const float4*)(xn+(size_t)r*1600);
    float4* cat4=(float4*)s_cat;
    for (int j=tid;j<400;j+=256){
      int l=j>>4, c4=j&15;
      cat4[l*32+c4]    = xs4[j];
      cat4[l*32+16+c4] = xr4[j];
    }
    for (int j=tid;j<475;j+=256) s_wig[j]=wig[(size_t)e*475+j];
    for (int j=tid;j<96;j+=256) ((float4*)s_rad)[j]=((const float4*)(radb+(size_t)e*384))[j];
    __syncthreads();
    if (tid<160){
      int pr=tid>>4, oct=tid&15;
      int ra=2*pr, rb=ra+1;
      bool hb = (rb<19);
      float a[8], b[8];
      #pragma unroll
      for (int q=0;q<8;q++){ a[q]=0.0f; b[q]=0.0f; }
      const float* wa_=s_wig+ra*25;
      const float* wb_=s_wig+(hb?rb:ra)*25;
      const float4* cp=(const float4*)s_cat;
      #pragma unroll
      for (int l=0;l<25;l++){
        float wa=wa_[l], wb=wb_[l];
        float4 c0=cp[l*32+oct*2], c1=cp[l*32+oct*2+1];
        a[0]+=wa*c0.x; a[1]+=wa*c0.y; a[2]+=wa*c0.z; a[3]+=wa*c0.w;
        a[4]+=wa*c1.x; a[5]+=wa*c1.y; a[6]+=wa*c1.z; a[7]+=wa*c1.w;
        b[0]+=wb*c0.x; b[1]+=wb*c0.y; b[2]+=wb*c0.z; b[3]+=wb*c0.w;
        b[4]+=wb*c1.x; b[5]+=wb*c1.y; b[6]+=wb*c1.z; b[7]+=wb*c1.w;
      }
      const float4* rp=(const float4*)s_rad;
      {
        int g=d_mg[ra];
        float4 r0=rp[g*32+oct*2], r1=rp[g*32+oct*2+1];
        a[0]*=r0.x; a[1]*=r0.y; a[2]*=r0.z; a[3]*=r0.w;
        a[4]*=r1.x; a[5]*=r1.y; a[6]*=r1.z; a[7]*=r1.w;
        int R=d_m2base[ra]+i*d_m2str[ra];
        msg_store(s_msg, R, oct, a);
      }
      if (hb){
        int g=d_mg[rb];
        float4 r0=rp[g*32+oct*2], r1=rp[g*32+oct*2+1];
        b[0]*=r0.x; b[1]*=r0.y; b[2]*=r0.z; b[3]*=r0.w;
        b[4]*=r1.x; b[5]*=r1.y; b[6]*=r1.z; b[7]*=r1.w;
        int R=d_m2base[rb]+i*d_m2str[rb];
        msg_store(s_msg, R, oct, b);
      }
    }
    __syncthreads();
  }
  int wv=tid>>6, lane=tid&63;
  int lanelo=lane&15, khi=lane>>4;
  // ---- vv = msg @ wsv_g (MFMA), *attn, -> bf16 s_vv ----
  {
    int nt0=wv*2, nt1=nt0+1;
    bf16x8 B0[4], B1[4];
    const int4* wp4=(const int4*)wsvp;
    int curg=-1;
    for (int rt=0;rt<6;rt++){
      int g=rt>>1;
      if (g!=curg){
        curg=g;
        #pragma unroll
        for (int kt=0;kt<4;kt++){
          int4 t0=wp4[g*2048+(kt*8+nt0)*64+lane];
          int4 t1=wp4[g*2048+(kt*8+nt1)*64+lane];
          B0[kt]=*(bf16x8*)&t0; B1[kt]=*(bf16x8*)&t1;
        }
      }
      int arow=rt*16+lanelo;
      bf16x8 A[4];
      #pragma unroll
      for (int kt=0;kt<4;kt++){
        int ch=(kt*4+khi)^(arow&7);
        A[kt]=*((const bf16x8*)(s_msg + arow*128 + (ch<<3)));
      }
      f32x4 acc0={0,0,0,0}, acc1={0,0,0,0};
      #pragma unroll
      for (int kt=0;kt<4;kt++){
        acc0=__builtin_amdgcn_mfma_f32_16x16x32_bf16(A[kt],B0[kt],acc0,0,0,0);
        acc1=__builtin_amdgcn_mfma_f32_16x16x32_bf16(A[kt],B1[kt],acc1,0,0,0);
      }
      int rbase=rt*16+khi*4;
      int col0=nt0*16+lanelo, col1=col0+16;
      #pragma unroll
      for (int q=0;q<4;q++){
        int row=rbase+q;
        int ei=s_r2e[row];
        float f0 = (ei>=0)? s_attn[ei][nt0] : 0.0f;
        float f1 = (ei>=0)? s_attn[ei][nt1] : 0.0f;
        s_vv[row*128 + (((col0>>3)^(row&7))<<3) + (col0&7)] = f2bf(acc0[q]*f0);
        s_vv[row*128 + (((col1>>3)^(row&7))<<3) + (col1&7)] = f2bf(acc1[q]*f1);
      }
    }
  }
  __syncthreads();
  // ---- oe = vv @ proj_g (MFMA) -> global bf16 [p][19][64] ----
  {
    int nt=wv;
    bf16x8 P[4];
    const int4* pp4=(const int4*)projp;
    int curg=-1;
    for (int rt=0;rt<6;rt++){
      int g=rt>>1;
      if (g!=curg){
        curg=g;
        #pragma unroll
        for (int kt=0;kt<4;kt++){
          int4 t=pp4[g*1024+(kt*4+nt)*64+lane];
          P[kt]=*(bf16x8*)&t;
        }
      }
      int arow=rt*16+lanelo;
      bf16x8 A[4];
      #pragma unroll
      for (int kt=0;kt<4;kt++){
        int ch=(kt*4+khi)^(arow&7);
        A[kt]=*((const bf16x8*)(s_vv + arow*128 + (ch<<3)));
      }
      f32x4 acc={0,0,0,0};
      #pragma unroll
      for (int kt=0;kt<4;kt++)
        acc=__builtin_amdgcn_mfma_f32_16x16x32_bf16(A[kt],P[kt],acc,0,0,0);
      int rbase=rt*16+khi*4;
      int col=nt*16+lanelo;
      #pragma unroll
      for (int q=0;q<4;q++){
        int row=rbase+q;
        int ei=s_r2e[row];
        if (ei>=0 && s_e[ei]>=0){
          int m=s_r2m[row];
          oe[((size_t)(p0+ei)*19+m)*64+col]=f2bf(acc[q]);
        }
      }
    }
  }
}

// ---------------- pass 2b: per-node gather: winv rotate + accumulate ----------------
__global__ __launch_bounds__(256) void attn_sum_kernel(const unsigned short* __restrict__ oe,
    const float* __restrict__ winv, const int* __restrict__ rowptr, const int* __restrict__ eix,
    float* __restrict__ x, int N){
  int n=blockIdx.x, tid=threadIdx.x;
  __shared__ float s_winv[475];
  __shared__ unsigned short s_oe[1216];   // [19][64] bf16
  int row0=rowptr[n];
  int cnt=rowptr[n+1]-row0;
  float4 acc0={0,0,0,0}, acc1={0,0,0,0};
  int it1=tid+256;
  for (int j=0;j<cnt;j++){
    int p=row0+j;
    int e=eix[p];
    for (int k2=tid;k2<475;k2+=256) s_winv[k2]=winv[(size_t)e*475+k2];
    for (int k2=tid;k2<152;k2+=256) ((int4*)s_oe)[k2]=((const int4*)(oe+(size_t)p*1216))[k2];
    __syncthreads();
    const unsigned* o2=(const unsigned*)s_oe;
    {
      int l=tid>>4, c4=tid&15;
      const float* wr=s_winv+l*19;
      #pragma unroll
      for (int m=0;m<19;m++){
        float w=wr[m];
        unsigned ua=o2[m*32+c4*2], ub=o2[m*32+c4*2+1];
        acc0.x+=w*bf2f((unsigned short)(ua&0xffffu));
        acc0.y+=w*bf2f((unsigned short)(ua>>16));
        acc0.z+=w*bf2f((unsigned short)(ub&0xffffu));
        acc0.w+=w*bf2f((unsigned short)(ub>>16));
      }
    }
    if (it1<400){
      int l=it1>>4, c4=it1&15;
      const float* wr=s_winv+l*19;
      #pragma unroll
      for (int m=0;m<19;m++){
        float w=wr[m];
        unsigned ua=o2[m*32+c4*2], ub=o2[m*32+c4*2+1];
        acc1.x+=w*bf2f((unsigned short)(ua&0xffffu));
        acc1.y+=w*bf2f((unsigned short)(ua>>16));
        acc1.z+=w*bf2f((unsigned short)(ub&0xffffu));
        acc1.w+=w*bf2f((unsigned short)(ub>>16));
      }
    }
    __syncthreads();
  }
  float4* xp=(float4*)(x+(size_t)n*1600);
  {
    float4 c=xp[tid];
    c.x+=acc0.x; c.y+=acc0.y; c.z+=acc0.z; c.w+=acc0.w;
    xp[tid]=c;
  }
  if (it1<400){
    float4 c=xp[it1];
    c.x+=acc1.x; c.y+=acc1.y; c.z+=acc1.z; c.w+=acc1.w;
    xp[it1]=c;
  }
}

// ---------------- S2 grid FFN via split-bf16 MFMA (one node/block, 4 waves) ----------------
// Chain: g = tg@xn -> hid = silu(g@W1+b1) -> o = hid@W2 -> out += fg@o
// Every GEMM is 3-term hi/lo: Ah*Bh + Al*Bh + Ah*Bl (operands exact to ~2^-18).
// Per-wave scratch (8KB) is reused g->hid->o; A-regs loaded before each overwrite.
// k-pad garbage in scratch is harmless: fg/tg A-frags are zero on padded k.
__global__ __launch_bounds__(256) void grid_ffn_mfma_kernel(const float* __restrict__ xn,
    const unsigned short* __restrict__ tgp, const unsigned short* __restrict__ fgp,
    const unsigned short* __restrict__ w1p, const unsigned short* __restrict__ w2p,
    const float* __restrict__ b1, float* __restrict__ x, int N){
  int n=blockIdx.x, tid=threadIdx.x, wv=tid>>6, lane=tid&63;
  int lanelo=lane&15, khi=lane>>4;
  __shared__ __align__(16) char s_mem[74240];
  unsigned short* s_w1=(unsigned short*)s_mem;             // hi 8192 | lo 8192 shorts (32KB)
  unsigned short* s_xn=(unsigned short*)(s_mem+32768);     // hi 2048 | lo 2048 shorts (8KB)
  float* s_b1=(float*)(s_mem+40960);                       // 128 f
  unsigned short* scr=(unsigned short*)(s_mem+41472)+(size_t)wv*4096;  // 8KB/wave
  for (int j=tid;j<2048;j+=256) ((int4*)s_w1)[j]=((const int4*)w1p)[j];
  if (tid<128) s_b1[tid]=b1[tid];
  { int4 z={0,0,0,0}; for (int j=tid;j<512;j+=256) ((int4*)s_xn)[j]=z; }
  __syncthreads();
  {
    const float* xr=xn+(size_t)n*1600;
    for (int j=tid;j<1600;j+=256){
      int k=j>>6, c=j&63;
      float v=xr[j];
      unsigned short h=f2bf(v);
      s_xn[c*32+k]=h;
      s_xn[2048+c*32+k]=f2bf(v-bf2f(h));
    }
  }
  __syncthreads();
  bf16x8 XBh[4],XBl[4];
  #pragma unroll
  for (int ct=0;ct<4;ct++){
    int o=(ct*16+lanelo)*32 + khi*8;
    XBh[ct]=*(const bf16x8*)(s_xn+o);
    XBl[ct]=*(const bf16x8*)(s_xn+2048+o);
  }
  f32x4 oacc[2][4];
  #pragma unroll
  for (int mt=0;mt<2;mt++)
    #pragma unroll
    for (int nt=0;nt<4;nt++){ f32x4 z={0,0,0,0}; oacc[mt][nt]=z; }
  for (int t=wv;t<18;t+=4){
    // ---- g = tg_tile @ xn (3-term) ----
    bf16x8 Atgh=*(const bf16x8*)(tgp + t*512 + lane*8);
    bf16x8 Atgl=*(const bf16x8*)(tgp + 9216 + t*512 + lane*8);
    #pragma unroll
    for (int ct=0;ct<4;ct++){
      f32x4 g={0,0,0,0};
      g=__builtin_amdgcn_mfma_f32_16x16x32_bf16(Atgh,XBh[ct],g,0,0,0);
      g=__builtin_amdgcn_mfma_f32_16x16x32_bf16(Atgl,XBh[ct],g,0,0,0);
      g=__builtin_amdgcn_mfma_f32_16x16x32_bf16(Atgh,XBl[ct],g,0,0,0);
      #pragma unroll
      for (int q=0;q<4;q++){
        int row=khi*4+q, col=ct*16+lanelo;
        int pos=row*64 + (((col>>3)^(row&7))<<3) + (col&7);
        float v=g[q]; unsigned short h=f2bf(v);
        scr[pos]=h; scr[1024+pos]=f2bf(v-bf2f(h));
      }
    }
    bf16x8 Agh[2],Agl[2];
    #pragma unroll
    for (int kt=0;kt<2;kt++){
      int o=lanelo*64 + (((kt*4+khi)^(lanelo&7))<<3);
      Agh[kt]=*(const bf16x8*)(scr+o);
      Agl[kt]=*(const bf16x8*)(scr+1024+o);
    }
    // ---- hid = silu(g@W1 + b1) (3-term); overwrites g planes (Ag in regs) ----
    #pragma unroll
    for (int nt=0;nt<8;nt++){
      f32x4 h={0,0,0,0};
      #pragma unroll
      for (int kt=0;kt<2;kt++){
        bf16x8 Bh=*(const bf16x8*)(s_w1 + (kt*8+nt)*512 + lane*8);
        bf16x8 Bl=*(const bf16x8*)(s_w1 + 8192 + (kt*8+nt)*512 + lane*8);
        h=__builtin_amdgcn_mfma_f32_16x16x32_bf16(Agh[kt],Bh,h,0,0,0);
        h=__builtin_amdgcn_mfma_f32_16x16x32_bf16(Agl[kt],Bh,h,0,0,0);
        h=__builtin_amdgcn_mfma_f32_16x16x32_bf16(Agh[kt],Bl,h,0,0,0);
      }
      #pragma unroll
      for (int q=0;q<4;q++){
        int row=khi*4+q, col=nt*16+lanelo;
        float v=silu_f(h[q]+s_b1[col]);
        int pos=row*128 + (((col>>3)^(row&7))<<3) + (col&7);
        unsigned short hh=f2bf(v);
        scr[pos]=hh; scr[2048+pos]=f2bf(v-bf2f(hh));
      }
    }
    bf16x8 Ahh[4],Ahl[4];
    #pragma unroll
    for (int kt=0;kt<4;kt++){
      int o=lanelo*128 + (((kt*4+khi)^(lanelo&7))<<3);
      Ahh[kt]=*(const bf16x8*)(scr+o);
      Ahl[kt]=*(const bf16x8*)(scr+2048+o);
    }
    // ---- o = hid @ W2 (3-term, W2 frags from global/L1); overwrites hid planes ----
    #pragma unroll
    for (int nt=0;nt<4;nt++){
      f32x4 o4={0,0,0,0};
      #pragma unroll
      for (int kt=0;kt<4;kt++){
        bf16x8 Bh=*(const bf16x8*)(w2p + (kt*4+nt)*512 + lane*8);
        bf16x8 Bl=*(const bf16x8*)(w2p + 8192 + (kt*4+nt)*512 + lane*8);
        o4=__builtin_amdgcn_mfma_f32_16x16x32_bf16(Ahh[kt],Bh,o4,0,0,0);
        o4=__builtin_amdgcn_mfma_f32_16x16x32_bf16(Ahl[kt],Bh,o4,0,0,0);
        o4=__builtin_amdgcn_mfma_f32_16x16x32_bf16(Ahh[kt],Bl,o4,0,0,0);
      }
      #pragma unroll
      for (int q=0;q<4;q++){
        int ch=nt*16+lanelo, rowk=khi*4+q;
        int pos=ch*32 + (((rowk>>3)^(ch&3))<<3) + (rowk&7);
        float v=o4[q]; unsigned short hh=f2bf(v);
        scr[pos]=hh; scr[2048+pos]=f2bf(v-bf2f(hh));
      }
    }
    // ---- out += fg_tile @ o (3-term; fg A-frags zero for k>=16) ----
    bf16x8 Boh[4],Bol[4];
    #pragma unroll
    for (int nt=0;nt<4;nt++){
      int ch=nt*16+lanelo;
      int o=ch*32 + ((khi^(ch&3))<<3);
      Boh[nt]=*(const bf16x8*)(scr+o);
      Bol[nt]=*(const bf16x8*)(scr+2048+o);
    }
    #pragma unroll
    for (int mt=0;mt<2;mt++){
      bf16x8 Afh=*(const bf16x8*)(fgp + (t*2+mt)*512 + lane*8);
      bf16x8 Afl=*(const bf16x8*)(fgp + 18432 + (t*2+mt)*512 + lane*8);
      #pragma unroll
      for (int nt=0;nt<4;nt++){
        oacc[mt][nt]=__builtin_amdgcn_mfma_f32_16x16x32_bf16(Afh,Boh[nt],oacc[mt][nt],0,0,0);
        oacc[mt][nt]=__builtin_amdgcn_mfma_f32_16x16x32_bf16(Afl,Boh[nt],oacc[mt][nt],0,0,0);
        oacc[mt][nt]=__builtin_amdgcn_mfma_f32_16x16x32_bf16(Afh,Bol[nt],oacc[mt][nt],0,0,0);
      }
    }
  }
  __syncthreads();
  float* pout=(float*)s_mem;   // alias W1 region: 4 waves x [32][64] fp32 (32KB)
  #pragma unroll
  for (int mt=0;mt<2;mt++)
    #pragma unroll
    for (int nt=0;nt<4;nt++)
      #pragma unroll
      for (int q=0;q<4;q++){
        int row=mt*16+khi*4+q, col=nt*16+lanelo;
        pout[wv*2048 + row*64 + col]=oacc[mt][nt][q];
      }
  __syncthreads();
  for (int j=tid;j<1600;j+=256)
    x[(size_t)n*1600+j] += pout[j]+pout[2048+j]+pout[4096+j]+pout[6144+j];
}

// ---------------- final energy head via split-bf16 MFMA ----------------
__global__ __launch_bounds__(256) void energy_mfma_kernel(const float* __restrict__ xn,
    const unsigned short* __restrict__ tgp, const float* __restrict__ fg,
    const unsigned short* __restrict__ enw1p, const float* __restrict__ b1,
    const float* __restrict__ w2, const float* __restrict__ b2,
    float* __restrict__ out, int N){
  int n=blockIdx.x, tid=threadIdx.x, wv=tid>>6, lane=tid&63;
  int lanelo=lane&15, khi=lane>>4;
  __shared__ __align__(16) char s_mem[59584];
  unsigned short* s_w1=(unsigned short*)s_mem;             // hi 8192 | lo 8192 shorts
  unsigned short* s_xn=(unsigned short*)(s_mem+32768);     // hi 2048 | lo 2048
  float* s_b1=(float*)(s_mem+40960);
  float* s_w2=(float*)(s_mem+41472);
  float* s_fg0=(float*)(s_mem+41984);                      // 288 f
  float* s_red=(float*)(s_mem+43136);
  unsigned short* scr=(unsigned short*)(s_mem+43200)+(size_t)wv*2048;  // 4KB/wave (g hi|lo)
  for (int j=tid;j<2048;j+=256) ((int4*)s_w1)[j]=((const int4*)enw1p)[j];
  if (tid<128){ s_b1[tid]=b1[tid]; s_w2[tid]=w2[tid]; }
  for (int j=tid;j<288;j+=256) s_fg0[j]=fg[j];
  { int4 z={0,0,0,0}; for (int j=tid;j<512;j+=256) ((int4*)s_xn)[j]=z; }
  __syncthreads();
  {
    const float* xr=xn+(size_t)n*1600;
    for (int j=tid;j<1600;j+=256){
      int k=j>>6, c=j&63;
      float v=xr[j];
      unsigned short h=f2bf(v);
      s_xn[c*32+k]=h;
      s_xn[2048+c*32+k]=f2bf(v-bf2f(h));
    }
  }
  __syncthreads();
  bf16x8 XBh[4],XBl[4];
  #pragma unroll
  for (int ct=0;ct<4;ct++){
    int o=(ct*16+lanelo)*32 + khi*8;
    XBh[ct]=*(const bf16x8*)(s_xn+o);
    XBl[ct]=*(const bf16x8*)(s_xn+2048+o);
  }
  float b2v=b2[0];
  float e=0.0f;
  for (int t=wv;t<18;t+=4){
    bf16x8 Atgh=*(const bf16x8*)(tgp + t*512 + lane*8);
    bf16x8 Atgl=*(const bf16x8*)(tgp + 9216 + t*512 + lane*8);
    #pragma unroll
    for (int ct=0;ct<4;ct++){
      f32x4 g={0,0,0,0};
      g=__builtin_amdgcn_mfma_f32_16x16x32_bf16(Atgh,XBh[ct],g,0,0,0);
      g=__builtin_amdgcn_mfma_f32_16x16x32_bf16(Atgl,XBh[ct],g,0,0,0);
      g=__builtin_amdgcn_mfma_f32_16x16x32_bf16(Atgh,XBl[ct],g,0,0,0);
      #pragma unroll
      for (int q=0;q<4;q++){
        int row=khi*4+q, col=ct*16+lanelo;
        int pos=row*64 + (((col>>3)^(row&7))<<3) + (col&7);
        float v=g[q]; unsigned short h=f2bf(v);
        scr[pos]=h; scr[1024+pos]=f2bf(v-bf2f(h));
      }
    }
    bf16x8 Agh[2],Agl[2];
    #pragma unroll
    for (int kt=0;kt<2;kt++){
      int o=lanelo*64 + (((kt*4+khi)^(lanelo&7))<<3);
      Agh[kt]=*(const bf16x8*)(scr+o);
      Agl[kt]=*(const bf16x8*)(scr+1024+o);
    }
    #pragma unroll
    for (int nt=0;nt<8;nt++){
      f32x4 h={0,0,0,0};
      #pragma unroll
      for (int kt=0;kt<2;kt++){
        bf16x8 Bh=*(const bf16x8*)(s_w1 + (kt*8+nt)*512 + lane*8);
        bf16x8 Bl=*(const bf16x8*)(s_w1 + 8192 + (kt*8+nt)*512 + lane*8);
        h=__builtin_amdgcn_mfma_f32_16x16x32_bf16(Agh[kt],Bh,h,0,0,0);
        h=__builtin_amdgcn_mfma_f32_16x16x32_bf16(Agl[kt],Bh,h,0,0,0);
        h=__builtin_amdgcn_mfma_f32_16x16x32_bf16(Agh[kt],Bl,h,0,0,0);
      }
      #pragma unroll
      for (int q=0;q<4;q++){
        int row=khi*4+q, col=nt*16+lanelo;
        float v=silu_f(h[q]+s_b1[col]);
        e += v*s_w2[col]*s_fg0[t*16+row];
      }
    }
    if (lanelo==0){
      #pragma unroll
      for (int q=0;q<4;q++) e += s_fg0[t*16+khi*4+q]*b2v;
    }
  }
  #pragma unroll
  for (int d=1;d<64;d<<=1) e += __shfl_xor(e,d);
  if (lane==0) s_red[wv]=e;
  __syncthreads();
  if (tid==0) out[n]=(s_red[0]+s_red[1]+s_red[2]+s_red[3])*(1.0f/2000.0f);
}

extern "C" void kernel_launch(void* const* d_in, const int* in_sizes, int n_in,
                              void* d_out, int out_size, void* d_ws, size_t ws_size,
                              hipStream_t stream){
  (void)n_in; (void)out_size; (void)ws_size;
  const float* ev   = (const float*)d_in[0];
  const float* wig  = (const float*)d_in[1];
  const float* winv = (const float*)d_in[2];
  const float* spe  = (const float*)d_in[3];
  const float* ese  = (const float*)d_in[4];
  const float* degW1= (const float*)d_in[5];
  const float* degb1= (const float*)d_in[6];
  const float* degW2= (const float*)d_in[7];
  const float* degb2= (const float*)d_in[8];
  const float* n1w  = (const float*)d_in[9];
  const float* radW1= (const float*)d_in[10];
  const float* radb1= (const float*)d_in[11];
  const float* radW2= (const float*)d_in[12];
  const float* radb2= (const float*)d_in[13];
  const float* so2W = (const float*)d_in[14];
  const float* aW   = (const float*)d_in[15];
  const float* aV   = (const float*)d_in[16];
  const float* vW   = (const float*)d_in[17];
  const float* pW   = (const float*)d_in[18];
  const float* n2w  = (const float*)d_in[19];
  const float* fW1  = (const float*)d_in[20];
  const float* fb1  = (const float*)d_in[21];
  const float* fW2  = (const float*)d_in[22];
  const float* tg   = (const float*)d_in[23];
  const float* fg   = (const float*)d_in[24];
  const float* fnw  = (const float*)d_in[25];
  const float* enW1 = (const float*)d_in[26];
  const float* enb1 = (const float*)d_in[27];
  const float* enW2 = (const float*)d_in[28];
  const float* enb2 = (const float*)d_in[29];
  const int* nsp = (const int*)d_in[30];
  const int* snd = (const int*)d_in[31];
  const int* rcv = (const int*)d_in[32];
  int N = in_sizes[30];
  int E = in_sizes[31];
  float* out = (float*)d_out;

  float* ws = (float*)d_ws;
  size_t off = 0;
  float* radbuf = ws + off; off += (size_t)E*384;
  float* logits = ws + off; off += (size_t)E*8;
  float* mx     = ws + off; off += (size_t)N*8;
  float* den    = ws + off; off += (size_t)N*8;
  float* x      = ws + off; off += (size_t)N*1600;
  float* xn     = ws + off; off += (size_t)N*1600;
  unsigned short* wsvb  = (unsigned short*)(ws + off); off += (size_t)6*16384/2;
  unsigned short* projb = (unsigned short*)(ws + off); off += (size_t)6*8192/2;
  int* cnt      = (int*)(ws + off); off += (size_t)N;
  int* rowptr   = (int*)(ws + off); off += (size_t)(N+1);
  int* fill     = (int*)(ws + off); off += (size_t)N;
  int* eixbuf   = (int*)(ws + off); off += (size_t)E;
  off = (off + 3) & ~((size_t)3);                       // 16B-align
  unsigned short* oebuf = (unsigned short*)(ws + off); off += (size_t)E*608;  // [E][19][64] bf16
  unsigned short* tgp   = (unsigned short*)(ws + off); off += 9216;    // hi+lo 18432 shorts
  unsigned short* fgp   = (unsigned short*)(ws + off); off += 18432;   // hi+lo 36864 shorts
  unsigned short* wwp   = (unsigned short*)(ws + off); off += 32768;   // 2 layers x (w1 hi/lo + w2 hi/lo)
  unsigned short* enw1p = (unsigned short*)(ws + off); off += 8192;    // hi+lo 16384 shorts

  // CSR by receiver + packed weights
  zero_cnt_kernel<<<(N+255)/256, 256, 0, stream>>>(cnt, N);
  csr_count_kernel<<<(E+255)/256, 256, 0, stream>>>(rcv, cnt, E);
  csr_scan_kernel<<<1, 256, 0, stream>>>(cnt, rowptr, fill, N);
  csr_fill_kernel<<<(E+255)/256, 256, 0, stream>>>(rcv, fill, eixbuf, E);
  wsvb_kernel<<<6, 256, 0, stream>>>(so2W, vW, wsvb);
  projb_kernel<<<6, 256, 0, stream>>>(pW, projb);
  pack_tg2_kernel<<<1, 256, 0, stream>>>(tg, tgp);
  pack_fg2_kernel<<<1, 256, 0, stream>>>(fg, fgp);
  for (int i=0;i<2;i++){
    unsigned short* wl = wwp + (size_t)i*32768;
    packB2_kernel<<<1, 256, 0, stream>>>(fW1 + (size_t)i*8192, wl, wl+8192, 64, 128);
    packB2_kernel<<<1, 256, 0, stream>>>(fW2 + (size_t)i*8192, wl+16384, wl+24576, 128, 64);
  }
  packB2_kernel<<<1, 256, 0, stream>>>(enW1, enw1p, enw1p+8192, 64, 128);

  deg_gather_kernel<<<N, 256, 0, stream>>>(ev, ese, nsp, spe, degW1, degb1, degW2, degb2,
                                           winv, snd, rowptr, eixbuf, x, N);

  for (int i=0;i<2;i++){
    rmsnorm_kernel<<<N, 256, 0, stream>>>(x, n1w + (size_t)i*320, xn, N);
    init_mxden_kernel<<<(N*8+255)/256, 256, 0, stream>>>(mx, den, N);
    rad_kernel<<<(E+3)/4, 256, 0, stream>>>(ev, ese, nsp, radW1 + (size_t)i*DIN*128, radb1 + (size_t)i*128,
                                            radW2 + (size_t)i*128*384, radb2 + (size_t)i*384,
                                            snd, rcv, radbuf, E);
    logits_kernel<<<E, 256, 0, stream>>>(xn, wig, radbuf, so2W + (size_t)i*24576,
                                         aW + (size_t)i*64*256, aV + (size_t)i*256,
                                         snd, rcv, logits, mx, E);
    den_kernel<<<(E*8+255)/256, 256, 0, stream>>>(logits, mx, rcv, den, E);
    attn_edge_kernel<<<(E+3)/4, 256, 0, stream>>>(xn, wig, radbuf,
                                                  wsvb + (size_t)i*3*16384, projb + (size_t)i*3*8192,
                                                  logits, mx, den, snd, rcv, eixbuf, oebuf, E);
    attn_sum_kernel<<<N, 256, 0, stream>>>(oebuf, winv, rowptr, eixbuf, x, N);
    rmsnorm_kernel<<<N, 256, 0, stream>>>(x, n2w + (size_t)i*320, xn, N);
    grid_ffn_mfma_kernel<<<N, 256, 0, stream>>>(xn, tgp, fgp,
                                                wwp + (size_t)i*32768, wwp + (size_t)i*32768 + 16384,
                                                fb1 + (size_t)i*128, x, N);
  }
  rmsnorm_kernel<<<N, 256, 0, stream>>>(x, fnw, xn, N);
  energy_mfma_kernel<<<N, 256, 0, stream>>>(xn, tgp, fg, enw1p, enb1, enW2, enb2, out, N);
}

// Round 4
// 4045.038 us; speedup vs baseline: 2.0857x; 1.2437x over previous
//
#include <hip/hip_runtime.h>
#include <hip/hip_bf16.h>
#include <math.h>

// EquiformerV2 block, fp32 activations. Round 10: degree-embedding MLP + radial MLP
// moved to split-bf16 MFMA via generic edge-parallel mlp_edge_kernel (16 edges = one
// M-tile per block); deg rotate+scatter reuses attn_sum structure (deg_sum_kernel).
// Grid FFN/energy on split-bf16 MFMA (round 9); attention SO2-conv on MFMA (round 7).
// E=40000 edges, N=2000 nodes, C=64, L2=25, M2=19, NL=2.

#define NRBF 600
#define DIN 728
#define GPTS 288

typedef __attribute__((ext_vector_type(8))) short bf16x8;
typedef __attribute__((ext_vector_type(4))) float f32x4;

__constant__ int d_mg[19] = {0,1,0,1,2,1,0,1,2,2,1,0,1,2,2,1,0,1,2};
__constant__ int d_loc[25] = {0,1,1,1,2,2,2,2,2,3,3,3,3,3,3,3,4,4,4,4,4,4,4,4,4};
// EB=4 group-major row layout: g0 rows 0..19 (pad to 32), g1 rows 32..63, g2 rows 64..87 (pad to 96)
__constant__ int d_row2e[96] = {
  0,0,0,0,0, 1,1,1,1,1, 2,2,2,2,2, 3,3,3,3,3, -1,-1,-1,-1,-1,-1,-1,-1,-1,-1,-1,-1,
  0,0,0,0,0,0,0,0, 1,1,1,1,1,1,1,1, 2,2,2,2,2,2,2,2, 3,3,3,3,3,3,3,3,
  0,0,0,0,0,0, 1,1,1,1,1,1, 2,2,2,2,2,2, 3,3,3,3,3,3, -1,-1,-1,-1,-1,-1,-1,-1};
__constant__ int d_row2m[96] = {
  0,2,6,11,16, 0,2,6,11,16, 0,2,6,11,16, 0,2,6,11,16, 0,0,0,0,0,0,0,0,0,0,0,0,
  1,3,5,7,10,12,15,17, 1,3,5,7,10,12,15,17, 1,3,5,7,10,12,15,17, 1,3,5,7,10,12,15,17,
  4,8,9,13,14,18, 4,8,9,13,14,18, 4,8,9,13,14,18, 4,8,9,13,14,18, 0,0,0,0,0,0,0,0};
// m -> (row base, per-edge stride) in the 96-row layout
__constant__ int d_m2base[19] = {0,32,1,33,64,34,2,35,65,66,36,3,37,67,68,38,4,39,69};
__constant__ int d_m2str[19]  = {5,8,5,8,6,8,5,8,6,6,8,5,8,6,6,8,5,8,6};

__device__ inline float silu_f(float v){ return v/(1.0f+__expf(-v)); }
__device__ inline float bf2f(unsigned short u){ return __uint_as_float(((unsigned)u)<<16); }
__device__ inline unsigned short f2bf(float f){
  unsigned b=__float_as_uint(f);
  return (unsigned short)((b + 0x7FFF + ((b>>16)&1)) >> 16);
}

__device__ inline void atomicMaxF(float* addr, float val){
  int* ia=(int*)addr;
  int old=*ia;
  while (__int_as_float(old) < val){
    int assumed=old;
    old = atomicCAS(ia, assumed, __float_as_int(val));
    if (old == assumed) break;
  }
}

// ---------------- CSR build ----------------
__global__ __launch_bounds__(256) void zero_cnt_kernel(int* cnt, int N){
  int i = blockIdx.x*256+threadIdx.x;
  if (i<N) cnt[i]=0;
}
__global__ __launch_bounds__(256) void csr_count_kernel(const int* __restrict__ rcv, int* cnt, int E){
  int i = blockIdx.x*256+threadIdx.x;
  if (i<E) atomicAdd(&cnt[rcv[i]],1);
}
__global__ __launch_bounds__(256) void csr_scan_kernel(const int* __restrict__ cnt,
    int* rowptr, int* fill, int N){
  __shared__ int s_part[256];
  int tid=threadIdx.x;
  int chunk=(N+255)/256;
  int lvals[12];
  int base=tid*chunk;
  int lsum=0;
  for (int i=0;i<chunk && i<12;i++){
    int v=(base+i<N)?cnt[base+i]:0;
    lvals[i]=lsum; lsum+=v;
  }
  s_part[tid]=lsum;
  __syncthreads();
  if (tid==0){
    int run=0;
    for (int t=0;t<256;t++){ int v=s_part[t]; s_part[t]=run; run+=v; }
  }
  __syncthreads();
  int off=s_part[tid];
  for (int i=0;i<chunk && i<12;i++){
    if (base+i<N){ rowptr[base+i]=off+lvals[i]; fill[base+i]=off+lvals[i]; }
  }
  if (tid==255) rowptr[N]=off+lsum;
}
__global__ __launch_bounds__(256) void csr_fill_kernel(const int* __restrict__ rcv,
    int* fill, int* eix, int E){
  int i = blockIdx.x*256+threadIdx.x;
  if (i<E){ int p=atomicAdd(&fill[rcv[i]],1); eix[p]=i; }
}

// ---------------- fused so2W@valW -> bf16 wsvb, MFMA-B-fragment packed ----------------
__global__ __launch_bounds__(256) void wsvb_kernel(const float* __restrict__ so2W,
    const float* __restrict__ valW, unsigned short* __restrict__ wsvb){
  int i=blockIdx.x/3, g=blockIdx.x%3;
  const float* A = so2W + (size_t)i*24576 + g*8192;   // [128][64]
  const float* B = valW + (size_t)i*24576 + g*8192;   // [64][128]
  unsigned short* C = wsvb + (size_t)blockIdx.x*16384;
  __shared__ float sB[8192];
  for (int j=threadIdx.x;j<2048;j+=256) ((float4*)sB)[j]=((const float4*)B)[j];
  __syncthreads();
  for (int idx=threadIdx.x; idx<16384; idx+=256){
    int k=idx>>7, j=idx&127;
    float acc=0;
    #pragma unroll 4
    for (int o=0;o<64;o++) acc += A[k*64+o]*sB[o*128+j];
    int pos = ((k>>5)*8 + (j>>4))*512 + (((k>>3)&3)*16 + (j&15))*8 + (k&7);
    C[pos]=f2bf(acc);
  }
}

// ---------------- projW -> bf16 [6][128][64], MFMA-B-fragment packed ----------------
__global__ __launch_bounds__(256) void projb_kernel(const float* __restrict__ pW,
    unsigned short* __restrict__ projb){
  const float* src = pW + (size_t)blockIdx.x*8192;
  unsigned short* dst = projb + (size_t)blockIdx.x*8192;
  for (int idx=threadIdx.x; idx<8192; idx+=256){
    int k=idx>>6, j=idx&63;
    int pos = ((k>>5)*4 + (j>>4))*512 + (((k>>3)&3)*16 + (j&15))*8 + (k&7);
    dst[pos]=f2bf(src[idx]);
  }
}

// ---------------- generic B-fragment packer, hi/lo split, K zero-padded to 32 ----------------
__global__ __launch_bounds__(256) void packB2g_kernel(const float* __restrict__ src,
    unsigned short* __restrict__ dh, unsigned short* __restrict__ dl, int K, int Nn){
  int ktiles=(K+31)>>5;
  int nnt=Nn>>4;
  int tot=ktiles*nnt*512;
  for (int idx=blockIdx.x*256+threadIdx.x; idx<tot; idx+=gridDim.x*256){
    int f=idx>>9, r=idx&511, lane=r>>3, j=r&7;
    int kt=f/nnt, nt=f-kt*nnt;
    int k=kt*32+(lane>>4)*8+j, c=nt*16+(lane&15);
    float v=(k<K)? src[k*Nn+c] : 0.0f;
    unsigned short h=f2bf(v);
    dh[idx]=h;
    dl[idx]=f2bf(v-bf2f(h));
  }
}

// ---------------- tg [288][25] -> A-frags per 16-row tile (K=32 pad), hi/lo ----------------
__global__ __launch_bounds__(256) void pack_tg2_kernel(const float* __restrict__ tg,
    unsigned short* __restrict__ tgp){   // hi [0..9216) | lo [9216..18432)
  int tid=threadIdx.x;
  for (int idx=tid; idx<9216; idx+=256){
    int t=idx>>9, r=idx&511, lane=r>>3, j=r&7;
    int kl=(lane>>4)*8+j, row=t*16+(lane&15);
    float v=(kl<25)? tg[row*25+kl] : 0.0f;
    unsigned short h=f2bf(v);
    tgp[idx]=h;
    tgp[9216+idx]=f2bf(v-bf2f(h));
  }
}

// ---------------- fg [25][288] -> A-frags [t][mt] (M pad 32, K=16 valid of 32), hi/lo ----------------
__global__ __launch_bounds__(256) void pack_fg2_kernel(const float* __restrict__ fg,
    unsigned short* __restrict__ fgp){   // hi [0..18432) | lo [18432..36864)
  int tid=threadIdx.x;
  for (int idx=tid; idx<18432; idx+=256){
    int f=idx>>9, r=idx&511, lane=r>>3, j=r&7;
    int t=f>>1, mt=f&1;
    int row=mt*16+(lane&15), k=(lane>>4)*8+j;
    float v=(row<25 && k<16)? fg[row*288+t*16+k] : 0.0f;
    unsigned short h=f2bf(v);
    fgp[idx]=h;
    fgp[18432+idx]=f2bf(v-bf2f(h));
  }
}

// ---------------- generic edge MLP via split-bf16 MFMA (16 edges = one M-tile / block) --------
// ee[16][736] built as A-frags (RBF+species concat) -> h1=silu(ee@W1+b1) -> out=h1@W2+b2
// mode 0: out bf16 [p][1216] (deg, CSR-ordered) ; mode 1: out fp32 [e][384] (radial)
__global__ __launch_bounds__(256) void mlp_edge_kernel(const float* __restrict__ ev,
    const float* __restrict__ ese, const int* __restrict__ nsp,
    const unsigned short* __restrict__ w1h, const unsigned short* __restrict__ w1l,
    const float* __restrict__ b1,
    const unsigned short* __restrict__ w2h, const unsigned short* __restrict__ w2l,
    const float* __restrict__ b2,
    const int* __restrict__ snd, const int* __restrict__ rcv, const int* __restrict__ eix,
    int use_eix, int nt2, int mode,
    unsigned short* __restrict__ outb, float* __restrict__ outf, int E){
  int tid=threadIdx.x, wv=tid>>6, lane=tid&63;
  int lanelo=lane&15, khi=lane>>4;
  int p0=blockIdx.x*16;
  __shared__ unsigned short s_eeh[11776], s_eel[11776];   // 23 A-frags (K=736 pad)
  __shared__ unsigned short s_h1h[2048], s_h1l[2048];     // [16][128] swizzled
  __shared__ float s_d[16]; __shared__ int s_ss[16], s_rs[16];
  if (tid<16){
    int p=p0+tid;
    int e=(p<E)? (use_eix? eix[p] : p) : -1;
    if (e>=0){
      float vx=ev[3*e], vy=ev[3*e+1], vz=ev[3*e+2];
      s_d[tid]=sqrtf(vx*vx+vy*vy+vz*vz+1e-12f);
      s_ss[tid]=nsp[snd[e]]; s_rs[tid]=nsp[rcv[e]];
    } else { s_d[tid]=0.0f; s_ss[tid]=0; s_rs[tid]=0; }
  }
  __syncthreads();
  const float step=5.0f/599.0f, inv_std=1.0f/(2.0f*step);
  for (int idx=tid; idx<11776; idx+=256){
    int f=idx>>9, r=idx&511, ln=r>>3, j=r&7;
    int k=f*32+((ln>>4)<<3)+j, row=ln&15;
    float v=0.0f;
    if (k<NRBF){ float t=(s_d[row]-k*step)*inv_std; v=__expf(-0.5f*t*t); }
    else if (k<NRBF+64) v=ese[s_ss[row]*128+(k-NRBF)];
    else if (k<DIN)     v=ese[s_rs[row]*128+64+(k-NRBF-64)];
    unsigned short h=f2bf(v);
    s_eeh[idx]=h; s_eel[idx]=f2bf(v-bf2f(h));
  }
  __syncthreads();
  // ---- GEMM1: [16][736] @ W1 -> h1[16][128] (3-term). Wave wv: ntiles wv*2, wv*2+1 ----
  {
    f32x4 acc0={0,0,0,0}, acc1={0,0,0,0};
    int nta=wv*2, ntb=nta+1;
    for (int kt=0;kt<23;kt++){
      bf16x8 Ah=*(const bf16x8*)(s_eeh + kt*512 + lane*8);
      bf16x8 Al=*(const bf16x8*)(s_eel + kt*512 + lane*8);
      const unsigned short* bpa=w1h+(size_t)(kt*8+nta)*512+lane*8;
      const unsigned short* bpl=w1l+(size_t)(kt*8+nta)*512+lane*8;
      bf16x8 Bh=*(const bf16x8*)bpa;
      bf16x8 Bl=*(const bf16x8*)bpl;
      acc0=__builtin_amdgcn_mfma_f32_16x16x32_bf16(Ah,Bh,acc0,0,0,0);
      acc0=__builtin_amdgcn_mfma_f32_16x16x32_bf16(Al,Bh,acc0,0,0,0);
      acc0=__builtin_amdgcn_mfma_f32_16x16x32_bf16(Ah,Bl,acc0,0,0,0);
      bf16x8 Bh2=*(const bf16x8*)(bpa+512);
      bf16x8 Bl2=*(const bf16x8*)(bpl+512);
      acc1=__builtin_amdgcn_mfma_f32_16x16x32_bf16(Ah,Bh2,acc1,0,0,0);
      acc1=__builtin_amdgcn_mfma_f32_16x16x32_bf16(Al,Bh2,acc1,0,0,0);
      acc1=__builtin_amdgcn_mfma_f32_16x16x32_bf16(Ah,Bl2,acc1,0,0,0);
    }
    #pragma unroll
    for (int q=0;q<4;q++){
      int row=khi*4+q;
      {
        int col=nta*16+lanelo;
        float v=silu_f(acc0[q]+b1[col]);
        int pos=row*128 + (((col>>3)^(row&7))<<3) + (col&7);
        unsigned short h=f2bf(v);
        s_h1h[pos]=h; s_h1l[pos]=f2bf(v-bf2f(h));
      }
      {
        int col=ntb*16+lanelo;
        float v=silu_f(acc1[q]+b1[col]);
        int pos=row*128 + (((col>>3)^(row&7))<<3) + (col&7);
        unsigned short h=f2bf(v);
        s_h1h[pos]=h; s_h1l[pos]=f2bf(v-bf2f(h));
      }
    }
  }
  __syncthreads();
  // ---- GEMM2: [16][128] @ W2[128][nt2*16] (3-term) ----
  bf16x8 Ahh[4],Ahl[4];
  #pragma unroll
  for (int kt=0;kt<4;kt++){
    int o=lanelo*128 + (((kt*4+khi)^(lanelo&7))<<3);
    Ahh[kt]=*(const bf16x8*)(s_h1h+o);
    Ahl[kt]=*(const bf16x8*)(s_h1l+o);
  }
  int ostride=nt2*16;
  for (int nt=wv; nt<nt2; nt+=4){
    f32x4 acc={0,0,0,0};
    #pragma unroll
    for (int kt=0;kt<4;kt++){
      const unsigned short* bp=w2h+(size_t)(kt*nt2+nt)*512+lane*8;
      bf16x8 Bh=*(const bf16x8*)bp;
      bf16x8 Bl=*(const bf16x8*)(w2l+(size_t)(kt*nt2+nt)*512+lane*8);
      acc=__builtin_amdgcn_mfma_f32_16x16x32_bf16(Ahh[kt],Bh,acc,0,0,0);
      acc=__builtin_amdgcn_mfma_f32_16x16x32_bf16(Ahl[kt],Bh,acc,0,0,0);
      acc=__builtin_amdgcn_mfma_f32_16x16x32_bf16(Ahh[kt],Bl,acc,0,0,0);
    }
    int col=nt*16+lanelo;
    float bb=b2[col];
    #pragma unroll
    for (int q=0;q<4;q++){
      int p=p0+khi*4+q;
      if (p<E){
        if (mode==0) outb[(size_t)p*ostride+col]=f2bf(acc[q]+bb);
        else         outf[(size_t)p*ostride+col]=acc[q]+bb;
      }
    }
  }
}

// ---------------- deg scatter: per node, winv rotate + scale + species base ----------------
__global__ __launch_bounds__(256) void deg_sum_kernel(const unsigned short* __restrict__ h2,
    const float* __restrict__ winv, const int* __restrict__ rowptr, const int* __restrict__ eix,
    const int* __restrict__ nsp, const float* __restrict__ spe,
    float* __restrict__ x, int N){
  int n=blockIdx.x, tid=threadIdx.x;
  __shared__ float s_winv[475];
  __shared__ unsigned short s_oe[1216];
  int row0=rowptr[n];
  int cnt=rowptr[n+1]-row0;
  float4 acc0={0,0,0,0}, acc1={0,0,0,0};
  int it1=tid+256;
  for (int j=0;j<cnt;j++){
    int p=row0+j;
    int e=eix[p];
    for (int k2=tid;k2<475;k2+=256) s_winv[k2]=winv[(size_t)e*475+k2];
    for (int k2=tid;k2<152;k2+=256) ((int4*)s_oe)[k2]=((const int4*)(h2+(size_t)p*1216))[k2];
    __syncthreads();
    const unsigned* o2=(const unsigned*)s_oe;
    {
      int l=tid>>4, c4=tid&15;
      const float* wr=s_winv+l*19;
      #pragma unroll
      for (int m=0;m<19;m++){
        float w=wr[m];
        unsigned ua=o2[m*32+c4*2], ub=o2[m*32+c4*2+1];
        acc0.x+=w*bf2f((unsigned short)(ua&0xffffu));
        acc0.y+=w*bf2f((unsigned short)(ua>>16));
        acc0.z+=w*bf2f((unsigned short)(ub&0xffffu));
        acc0.w+=w*bf2f((unsigned short)(ub>>16));
      }
    }
    if (it1<400){
      int l=it1>>4, c4=it1&15;
      const float* wr=s_winv+l*19;
      #pragma unroll
      for (int m=0;m<19;m++){
        float w=wr[m];
        unsigned ua=o2[m*32+c4*2], ub=o2[m*32+c4*2+1];
        acc1.x+=w*bf2f((unsigned short)(ua&0xffffu));
        acc1.y+=w*bf2f((unsigned short)(ua>>16));
        acc1.z+=w*bf2f((unsigned short)(ub&0xffffu));
        acc1.w+=w*bf2f((unsigned short)(ub>>16));
      }
    }
    __syncthreads();
  }
  int sp=nsp[n];
  const float4* sp4=(const float4*)(spe+(size_t)sp*64);
  float4* xp=(float4*)(x+(size_t)n*1600);
  {
    int l=tid>>4, c4=tid&15;
    float4 base=(l==0)? sp4[c4] : make_float4(0,0,0,0);
    float4 o;
    o.x=base.x+0.05f*acc0.x; o.y=base.y+0.05f*acc0.y;
    o.z=base.z+0.05f*acc0.z; o.w=base.w+0.05f*acc0.w;
    xp[tid]=o;
  }
  if (it1<400){
    float4 o;
    o.x=0.05f*acc1.x; o.y=0.05f*acc1.y; o.z=0.05f*acc1.z; o.w=0.05f*acc1.w;
    xp[it1]=o;
  }
}

// ---------------- per-degree RMS norm ----------------
__global__ __launch_bounds__(256) void rmsnorm_kernel(const float* __restrict__ x,
    const float* __restrict__ w, float* __restrict__ xn, int N){
  int n = blockIdx.x, tid = threadIdx.x;
  __shared__ float s_x[1600];
  __shared__ float s_part[256];
  __shared__ float s_ms[64];
  const float* xr = x + (size_t)n*1600;
  for (int j=tid;j<1600;j+=256) s_x[j]=xr[j];
  __syncthreads();
  {
    int c = tid&63, seg = tid>>6;
    float acc=0;
    for (int l=seg;l<25;l+=4){ float v=s_x[l*64+c]; acc+=v*v; }
    s_part[tid]=acc;
  }
  __syncthreads();
  if (tid<64){
    float m=(s_part[tid]+s_part[tid+64]+s_part[tid+128]+s_part[tid+192])*(1.0f/25.0f);
    s_ms[tid]=rsqrtf(m+1e-6f);
  }
  __syncthreads();
  float* xo = xn + (size_t)n*1600;
  for (int j=tid;j<1600;j+=256){
    int l=j>>6, c=j&63;
    xo[j]=s_x[j]*s_ms[c]*w[d_loc[l]*64+c];
  }
}

__global__ __launch_bounds__(256) void init_mxden_kernel(float* mx, float* den, int N){
  int idx = blockIdx.x*256+threadIdx.x;
  if (idx < N*8){ mx[idx]=-3.0e38f; den[idx]=0.0f; }
}

// ---------------- pass 1: m=0 path -> alpha logits ----------------
__global__ __launch_bounds__(256) void logits_kernel(const float* __restrict__ xn,
    const float* __restrict__ wig, const float* __restrict__ radb,
    const float* __restrict__ so2W, const float* __restrict__ alphaW, const float* __restrict__ alphaV,
    const int* __restrict__ snd, const int* __restrict__ rcv,
    float* __restrict__ logits, float* __restrict__ mx, int E){
  int e = blockIdx.x, tid = threadIdx.x;
  __shared__ float s_cat[3200];
  __shared__ float s_wig0[25];
  __shared__ float s_msg0[128];
  __shared__ float s_sh0[64];
  __shared__ float s_a[256];
  int s = snd[e], r = rcv[e];
  const float4* xs4 = (const float4*)(xn + (size_t)s*1600);
  const float4* xr4 = (const float4*)(xn + (size_t)r*1600);
  float4* cat4 = (float4*)s_cat;
  for (int j=tid;j<400;j+=256){
    int l=j>>4, c4=j&15;
    cat4[l*32+c4]    = xs4[j];
    cat4[l*32+16+c4] = xr4[j];
  }
  if (tid<25) s_wig0[tid]=wig[(size_t)e*475+tid];
  __syncthreads();
  if (tid<128){
    float acc=0;
    #pragma unroll
    for (int l=0;l<25;l++) acc += s_wig0[l]*s_cat[l*128+tid];
    s_msg0[tid]=acc*radb[(size_t)e*384+tid];
  }
  __syncthreads();
  if (tid<64){
    float acc=0;
    #pragma unroll
    for (int k=0;k<128;k++) acc += s_msg0[k]*so2W[k*64+tid];
    s_sh0[tid]=silu_f(acc);
  }
  __syncthreads();
  {
    float acc=0;
    #pragma unroll
    for (int o=0;o<64;o++) acc += s_sh0[o]*alphaW[o*256+tid];
    s_a[tid]=silu_f(acc)*alphaV[tid];
  }
  __syncthreads();
  if (tid<8){
    float lg=0;
    #pragma unroll
    for (int q=0;q<32;q++) lg += s_a[tid*32+q];
    logits[(size_t)e*8+tid]=lg;
    atomicMaxF(&mx[r*8+tid], lg);
  }
}

__global__ __launch_bounds__(256) void den_kernel(const float* __restrict__ logits,
    const float* __restrict__ mx, const int* __restrict__ rcv,
    float* __restrict__ den, int E){
  int idx = blockIdx.x*256+threadIdx.x;
  if (idx >= E*8) return;
  int e = idx>>3, hd = idx&7, r = rcv[e];
  atomicAdd(&den[r*8+hd], __expf(logits[idx]-mx[r*8+hd]));
}

// ---------------- pass 2a: edge-parallel MFMA SO2-conv (4 CSR edges / block) ----------------
__device__ inline void msg_store(unsigned short* smem, int R, int oct, const float* v){
  unsigned u0=((unsigned)f2bf(v[1])<<16)|f2bf(v[0]);
  unsigned u1=((unsigned)f2bf(v[3])<<16)|f2bf(v[2]);
  unsigned u2=((unsigned)f2bf(v[5])<<16)|f2bf(v[4]);
  unsigned u3=((unsigned)f2bf(v[7])<<16)|f2bf(v[6]);
  int4 t; t.x=(int)u0; t.y=(int)u1; t.z=(int)u2; t.w=(int)u3;
  *((int4*)(smem + R*128 + ((oct^(R&7))<<3))) = t;
}

__global__ __launch_bounds__(256) void attn_edge_kernel(const float* __restrict__ xn,
    const float* __restrict__ wig, const float* __restrict__ radb,
    const unsigned short* __restrict__ wsvp, const unsigned short* __restrict__ projp,
    const float* __restrict__ logits, const float* __restrict__ mx, const float* __restrict__ den,
    const int* __restrict__ snd, const int* __restrict__ rcv, const int* __restrict__ eix,
    unsigned short* __restrict__ oe, int E){
  int tid = threadIdx.x;
  int p0 = blockIdx.x*4;
  __shared__ unsigned short s_msg[12288];   // [96][128] bf16, chunk-swizzled
  __shared__ unsigned short s_vv[12288];
  __shared__ float s_cat[3200];
  __shared__ float s_wig[475];
  __shared__ float s_rad[384];
  __shared__ float s_attn[4][8];
  __shared__ int s_r2e[96], s_r2m[96];
  __shared__ int s_e[4], s_s[4], s_r[4];
  int ne = E - p0; if (ne>4) ne=4;
  if (tid<4){
    int ok = (tid<ne);
    int e = ok? eix[p0+tid] : -1;
    s_e[tid]=e;
    s_s[tid]= ok? snd[e] : 0;
    s_r[tid]= ok? rcv[e] : 0;
  }
  { int4 z={0,0,0,0}; for (int j=tid;j<1536;j+=256) ((int4*)s_msg)[j]=z; }
  for (int j=tid;j<96;j+=256){ s_r2e[j]=d_row2e[j]; s_r2m[j]=d_row2m[j]; }
  __syncthreads();
  if (tid<32){
    int i=tid>>3, h=tid&7;
    int e=s_e[i];
    float a=0.0f;
    if (e>=0){
      int r=s_r[i];
      a = __expf(logits[(size_t)e*8+h]-mx[r*8+h])/(den[r*8+h]+1e-12f);
    }
    s_attn[i][h]=a;
  }
  // ---- msg phase: per edge, fp32 rotate * rad -> bf16 swizzled LDS ----
  for (int i=0;i<ne;i++){
    int e=s_e[i], s=s_s[i], r=s_r[i];
    const float4* xs4=(const float4*)(xn+(size_t)s*1600);
    const float4* xr4=(const float4*)(xn+(size_t)r*1600);
    float4* cat4=(float4*)s_cat;
    for (int j=tid;j<400;j+=256){
      int l=j>>4, c4=j&15;
      cat4[l*32+c4]    = xs4[j];
      cat4[l*32+16+c4] = xr4[j];
    }
    for (int j=tid;j<475;j+=256) s_wig[j]=wig[(size_t)e*475+j];
    for (int j=tid;j<96;j+=256) ((float4*)s_rad)[j]=((const float4*)(radb+(size_t)e*384))[j];
    __syncthreads();
    if (tid<160){
      int pr=tid>>4, oct=tid&15;
      int ra=2*pr, rb=ra+1;
      bool hb = (rb<19);
      float a[8], b[8];
      #pragma unroll
      for (int q=0;q<8;q++){ a[q]=0.0f; b[q]=0.0f; }
      const float* wa_=s_wig+ra*25;
      const float* wb_=s_wig+(hb?rb:ra)*25;
      const float4* cp=(const float4*)s_cat;
      #pragma unroll
      for (int l=0;l<25;l++){
        float wa=wa_[l], wb=wb_[l];
        float4 c0=cp[l*32+oct*2], c1=cp[l*32+oct*2+1];
        a[0]+=wa*c0.x; a[1]+=wa*c0.y; a[2]+=wa*c0.z; a[3]+=wa*c0.w;
        a[4]+=wa*c1.x; a[5]+=wa*c1.y; a[6]+=wa*c1.z; a[7]+=wa*c1.w;
        b[0]+=wb*c0.x; b[1]+=wb*c0.y; b[2]+=wb*c0.z; b[3]+=wb*c0.w;
        b[4]+=wb*c1.x; b[5]+=wb*c1.y; b[6]+=wb*c1.z; b[7]+=wb*c1.w;
      }
      const float4* rp=(const float4*)s_rad;
      {
        int g=d_mg[ra];
        float4 r0=rp[g*32+oct*2], r1=rp[g*32+oct*2+1];
        a[0]*=r0.x; a[1]*=r0.y; a[2]*=r0.z; a[3]*=r0.w;
        a[4]*=r1.x; a[5]*=r1.y; a[6]*=r1.z; a[7]*=r1.w;
        int R=d_m2base[ra]+i*d_m2str[ra];
        msg_store(s_msg, R, oct, a);
      }
      if (hb){
        int g=d_mg[rb];
        float4 r0=rp[g*32+oct*2], r1=rp[g*32+oct*2+1];
        b[0]*=r0.x; b[1]*=r0.y; b[2]*=r0.z; b[3]*=r0.w;
        b[4]*=r1.x; b[5]*=r1.y; b[6]*=r1.z; b[7]*=r1.w;
        int R=d_m2base[rb]+i*d_m2str[rb];
        msg_store(s_msg, R, oct, b);
      }
    }
    __syncthreads();
  }
  int wv=tid>>6, lane=tid&63;
  int lanelo=lane&15, khi=lane>>4;
  // ---- vv = msg @ wsv_g (MFMA), *attn, -> bf16 s_vv ----
  {
    int nt0=wv*2, nt1=nt0+1;
    bf16x8 B0[4], B1[4];
    const int4* wp4=(const int4*)wsvp;
    int curg=-1;
    for (int rt=0;rt<6;rt++){
      int g=rt>>1;
      if (g!=curg){
        curg=g;
        #pragma unroll
        for (int kt=0;kt<4;kt++){
          int4 t0=wp4[g*2048+(kt*8+nt0)*64+lane];
          int4 t1=wp4[g*2048+(kt*8+nt1)*64+lane];
          B0[kt]=*(bf16x8*)&t0; B1[kt]=*(bf16x8*)&t1;
        }
      }
      int arow=rt*16+lanelo;
      bf16x8 A[4];
      #pragma unroll
      for (int kt=0;kt<4;kt++){
        int ch=(kt*4+khi)^(arow&7);
        A[kt]=*((const bf16x8*)(s_msg + arow*128 + (ch<<3)));
      }
      f32x4 acc0={0,0,0,0}, acc1={0,0,0,0};
      #pragma unroll
      for (int kt=0;kt<4;kt++){
        acc0=__builtin_amdgcn_mfma_f32_16x16x32_bf16(A[kt],B0[kt],acc0,0,0,0);
        acc1=__builtin_amdgcn_mfma_f32_16x16x32_bf16(A[kt],B1[kt],acc1,0,0,0);
      }
      int rbase=rt*16+khi*4;
      int col0=nt0*16+lanelo, col1=col0+16;
      #pragma unroll
      for (int q=0;q<4;q++){
        int row=rbase+q;
        int ei=s_r2e[row];
        float f0 = (ei>=0)? s_attn[ei][nt0] : 0.0f;
        float f1 = (ei>=0)? s_attn[ei][nt1] : 0.0f;
        s_vv[row*128 + (((col0>>3)^(row&7))<<3) + (col0&7)] = f2bf(acc0[q]*f0);
        s_vv[row*128 + (((col1>>3)^(row&7))<<3) + (col1&7)] = f2bf(acc1[q]*f1);
      }
    }
  }
  __syncthreads();
  // ---- oe = vv @ proj_g (MFMA) -> global bf16 [p][19][64] ----
  {
    int nt=wv;
    bf16x8 P[4];
    const int4* pp4=(const int4*)projp;
    int curg=-1;
    for (int rt=0;rt<6;rt++){
      int g=rt>>1;
      if (g!=curg){
        curg=g;
        #pragma unroll
        for (int kt=0;kt<4;kt++){
          int4 t=pp4[g*1024+(kt*4+nt)*64+lane];
          P[kt]=*(bf16x8*)&t;
        }
      }
      int arow=rt*16+lanelo;
      bf16x8 A[4];
      #pragma unroll
      for (int kt=0;kt<4;kt++){
        int ch=(kt*4+khi)^(arow&7);
        A[kt]=*((const bf16x8*)(s_vv + arow*128 + (ch<<3)));
      }
      f32x4 acc={0,0,0,0};
      #pragma unroll
      for (int kt=0;kt<4;kt++)
        acc=__builtin_amdgcn_mfma_f32_16x16x32_bf16(A[kt],P[kt],acc,0,0,0);
      int rbase=rt*16+khi*4;
      int col=nt*16+lanelo;
      #pragma unroll
      for (int q=0;q<4;q++){
        int row=rbase+q;
        int ei=s_r2e[row];
        if (ei>=0 && s_e[ei]>=0){
          int m=s_r2m[row];
          oe[((size_t)(p0+ei)*19+m)*64+col]=f2bf(acc[q]);
        }
      }
    }
  }
}

// ---------------- pass 2b: per-node gather: winv rotate + accumulate ----------------
__global__ __launch_bounds__(256) void attn_sum_kernel(const unsigned short* __restrict__ oe,
    const float* __restrict__ winv, const int* __restrict__ rowptr, const int* __restrict__ eix,
    float* __restrict__ x, int N){
  int n=blockIdx.x, tid=threadIdx.x;
  __shared__ float s_winv[475];
  __shared__ unsigned short s_oe[1216];   // [19][64] bf16
  int row0=rowptr[n];
  int cnt=rowptr[n+1]-row0;
  float4 acc0={0,0,0,0}, acc1={0,0,0,0};
  int it1=tid+256;
  for (int j=0;j<cnt;j++){
    int p=row0+j;
    int e=eix[p];
    for (int k2=tid;k2<475;k2+=256) s_winv[k2]=winv[(size_t)e*475+k2];
    for (int k2=tid;k2<152;k2+=256) ((int4*)s_oe)[k2]=((const int4*)(oe+(size_t)p*1216))[k2];
    __syncthreads();
    const unsigned* o2=(const unsigned*)s_oe;
    {
      int l=tid>>4, c4=tid&15;
      const float* wr=s_winv+l*19;
      #pragma unroll
      for (int m=0;m<19;m++){
        float w=wr[m];
        unsigned ua=o2[m*32+c4*2], ub=o2[m*32+c4*2+1];
        acc0.x+=w*bf2f((unsigned short)(ua&0xffffu));
        acc0.y+=w*bf2f((unsigned short)(ua>>16));
        acc0.z+=w*bf2f((unsigned short)(ub&0xffffu));
        acc0.w+=w*bf2f((unsigned short)(ub>>16));
      }
    }
    if (it1<400){
      int l=it1>>4, c4=it1&15;
      const float* wr=s_winv+l*19;
      #pragma unroll
      for (int m=0;m<19;m++){
        float w=wr[m];
        unsigned ua=o2[m*32+c4*2], ub=o2[m*32+c4*2+1];
        acc1.x+=w*bf2f((unsigned short)(ua&0xffffu));
        acc1.y+=w*bf2f((unsigned short)(ua>>16));
        acc1.z+=w*bf2f((unsigned short)(ub&0xffffu));
        acc1.w+=w*bf2f((unsigned short)(ub>>16));
      }
    }
    __syncthreads();
  }
  float4* xp=(float4*)(x+(size_t)n*1600);
  {
    float4 c=xp[tid];
    c.x+=acc0.x; c.y+=acc0.y; c.z+=acc0.z; c.w+=acc0.w;
    xp[tid]=c;
  }
  if (it1<400){
    float4 c=xp[it1];
    c.x+=acc1.x; c.y+=acc1.y; c.z+=acc1.z; c.w+=acc1.w;
    xp[it1]=c;
  }
}

// ---------------- S2 grid FFN via split-bf16 MFMA (one node/block, 4 waves) ----------------
__global__ __launch_bounds__(256) void grid_ffn_mfma_kernel(const float* __restrict__ xn,
    const unsigned short* __restrict__ tgp, const unsigned short* __restrict__ fgp,
    const unsigned short* __restrict__ w1p, const unsigned short* __restrict__ w2p,
    const float* __restrict__ b1, float* __restrict__ x, int N){
  int n=blockIdx.x, tid=threadIdx.x, wv=tid>>6, lane=tid&63;
  int lanelo=lane&15, khi=lane>>4;
  __shared__ __align__(16) char s_mem[74240];
  unsigned short* s_w1=(unsigned short*)s_mem;             // hi 8192 | lo 8192 shorts (32KB)
  unsigned short* s_xn=(unsigned short*)(s_mem+32768);     // hi 2048 | lo 2048 shorts (8KB)
  float* s_b1=(float*)(s_mem+40960);                       // 128 f
  unsigned short* scr=(unsigned short*)(s_mem+41472)+(size_t)wv*4096;  // 8KB/wave
  for (int j=tid;j<2048;j+=256) ((int4*)s_w1)[j]=((const int4*)w1p)[j];
  if (tid<128) s_b1[tid]=b1[tid];
  { int4 z={0,0,0,0}; for (int j=tid;j<512;j+=256) ((int4*)s_xn)[j]=z; }
  __syncthreads();
  {
    const float* xr=xn+(size_t)n*1600;
    for (int j=tid;j<1600;j+=256){
      int k=j>>6, c=j&63;
      float v=xr[j];
      unsigned short h=f2bf(v);
      s_xn[c*32+k]=h;
      s_xn[2048+c*32+k]=f2bf(v-bf2f(h));
    }
  }
  __syncthreads();
  bf16x8 XBh[4],XBl[4];
  #pragma unroll
  for (int ct=0;ct<4;ct++){
    int o=(ct*16+lanelo)*32 + khi*8;
    XBh[ct]=*(const bf16x8*)(s_xn+o);
    XBl[ct]=*(const bf16x8*)(s_xn+2048+o);
  }
  f32x4 oacc[2][4];
  #pragma unroll
  for (int mt=0;mt<2;mt++)
    #pragma unroll
    for (int nt=0;nt<4;nt++){ f32x4 z={0,0,0,0}; oacc[mt][nt]=z; }
  for (int t=wv;t<18;t+=4){
    // ---- g = tg_tile @ xn (3-term) ----
    bf16x8 Atgh=*(const bf16x8*)(tgp + t*512 + lane*8);
    bf16x8 Atgl=*(const bf16x8*)(tgp + 9216 + t*512 + lane*8);
    #pragma unroll
    for (int ct=0;ct<4;ct++){
      f32x4 g={0,0,0,0};
      g=__builtin_amdgcn_mfma_f32_16x16x32_bf16(Atgh,XBh[ct],g,0,0,0);
      g=__builtin_amdgcn_mfma_f32_16x16x32_bf16(Atgl,XBh[ct],g,0,0,0);
      g=__builtin_amdgcn_mfma_f32_16x16x32_bf16(Atgh,XBl[ct],g,0,0,0);
      #pragma unroll
      for (int q=0;q<4;q++){
        int row=khi*4+q, col=ct*16+lanelo;
        int pos=row*64 + (((col>>3)^(row&7))<<3) + (col&7);
        float v=g[q]; unsigned short h=f2bf(v);
        scr[pos]=h; scr[1024+pos]=f2bf(v-bf2f(h));
      }
    }
    bf16x8 Agh[2],Agl[2];
    #pragma unroll
    for (int kt=0;kt<2;kt++){
      int o=lanelo*64 + (((kt*4+khi)^(lanelo&7))<<3);
      Agh[kt]=*(const bf16x8*)(scr+o);
      Agl[kt]=*(const bf16x8*)(scr+1024+o);
    }
    // ---- hid = silu(g@W1 + b1) (3-term) ----
    #pragma unroll
    for (int nt=0;nt<8;nt++){
      f32x4 h={0,0,0,0};
      #pragma unroll
      for (int kt=0;kt<2;kt++){
        bf16x8 Bh=*(const bf16x8*)(s_w1 + (kt*8+nt)*512 + lane*8);
        bf16x8 Bl=*(const bf16x8*)(s_w1 + 8192 + (kt*8+nt)*512 + lane*8);
        h=__builtin_amdgcn_mfma_f32_16x16x32_bf16(Agh[kt],Bh,h,0,0,0);
        h=__builtin_amdgcn_mfma_f32_16x16x32_bf16(Agl[kt],Bh,h,0,0,0);
        h=__builtin_amdgcn_mfma_f32_16x16x32_bf16(Agh[kt],Bl,h,0,0,0);
      }
      #pragma unroll
      for (int q=0;q<4;q++){
        int row=khi*4+q, col=nt*16+lanelo;
        float v=silu_f(h[q]+s_b1[col]);
        int pos=row*128 + (((col>>3)^(row&7))<<3) + (col&7);
        unsigned short hh=f2bf(v);
        scr[pos]=hh; scr[2048+pos]=f2bf(v-bf2f(hh));
      }
    }
    bf16x8 Ahh[4],Ahl[4];
    #pragma unroll
    for (int kt=0;kt<4;kt++){
      int o=lanelo*128 + (((kt*4+khi)^(lanelo&7))<<3);
      Ahh[kt]=*(const bf16x8*)(scr+o);
      Ahl[kt]=*(const bf16x8*)(scr+2048+o);
    }
    // ---- o = hid @ W2 (3-term, W2 frags from global/L1) ----
    #pragma unroll
    for (int nt=0;nt<4;nt++){
      f32x4 o4={0,0,0,0};
      #pragma unroll
      for (int kt=0;kt<4;kt++){
        bf16x8 Bh=*(const bf16x8*)(w2p + (kt*4+nt)*512 + lane*8);
        bf16x8 Bl=*(const bf16x8*)(w2p + 8192 + (kt*4+nt)*512 + lane*8);
        o4=__builtin_amdgcn_mfma_f32_16x16x32_bf16(Ahh[kt],Bh,o4,0,0,0);
        o4=__builtin_amdgcn_mfma_f32_16x16x32_bf16(Ahl[kt],Bh,o4,0,0,0);
        o4=__builtin_amdgcn_mfma_f32_16x16x32_bf16(Ahh[kt],Bl,o4,0,0,0);
      }
      #pragma unroll
      for (int q=0;q<4;q++){
        int ch=nt*16+lanelo, rowk=khi*4+q;
        int pos=ch*32 + (((rowk>>3)^(ch&3))<<3) + (rowk&7);
        float v=o4[q]; unsigned short hh=f2bf(v);
        scr[pos]=hh; scr[2048+pos]=f2bf(v-bf2f(hh));
      }
    }
    // ---- out += fg_tile @ o (3-term; fg A-frags zero for k>=16) ----
    bf16x8 Boh[4],Bol[4];
    #pragma unroll
    for (int nt=0;nt<4;nt++){
      int ch=nt*16+lanelo;
      int o=ch*32 + ((khi^(ch&3))<<3);
      Boh[nt]=*(const bf16x8*)(scr+o);
      Bol[nt]=*(const bf16x8*)(scr+2048+o);
    }
    #pragma unroll
    for (int mt=0;mt<2;mt++){
      bf16x8 Afh=*(const bf16x8*)(fgp + (t*2+mt)*512 + lane*8);
      bf16x8 Afl=*(const bf16x8*)(fgp + 18432 + (t*2+mt)*512 + lane*8);
      #pragma unroll
      for (int nt=0;nt<4;nt++){
        oacc[mt][nt]=__builtin_amdgcn_mfma_f32_16x16x32_bf16(Afh,Boh[nt],oacc[mt][nt],0,0,0);
        oacc[mt][nt]=__builtin_amdgcn_mfma_f32_16x16x32_bf16(Afl,Boh[nt],oacc[mt][nt],0,0,0);
        oacc[mt][nt]=__builtin_amdgcn_mfma_f32_16x16x32_bf16(Afh,Bol[nt],oacc[mt][nt],0,0,0);
      }
    }
  }
  __syncthreads();
  float* pout=(float*)s_mem;   // alias W1 region: 4 waves x [32][64] fp32 (32KB)
  #pragma unroll
  for (int mt=0;mt<2;mt++)
    #pragma unroll
    for (int nt=0;nt<4;nt++)
      #pragma unroll
      for (int q=0;q<4;q++){
        int row=mt*16+khi*4+q, col=nt*16+lanelo;
        pout[wv*2048 + row*64 + col]=oacc[mt][nt][q];
      }
  __syncthreads();
  for (int j=tid;j<1600;j+=256)
    x[(size_t)n*1600+j] += pout[j]+pout[2048+j]+pout[4096+j]+pout[6144+j];
}

// ---------------- final energy head via split-bf16 MFMA ----------------
__global__ __launch_bounds__(256) void energy_mfma_kernel(const float* __restrict__ xn,
    const unsigned short* __restrict__ tgp, const float* __restrict__ fg,
    const unsigned short* __restrict__ enw1p, const float* __restrict__ b1,
    const float* __restrict__ w2, const float* __restrict__ b2,
    float* __restrict__ out, int N){
  int n=blockIdx.x, tid=threadIdx.x, wv=tid>>6, lane=tid&63;
  int lanelo=lane&15, khi=lane>>4;
  __shared__ __align__(16) char s_mem[59584];
  unsigned short* s_w1=(unsigned short*)s_mem;             // hi 8192 | lo 8192 shorts
  unsigned short* s_xn=(unsigned short*)(s_mem+32768);     // hi 2048 | lo 2048
  float* s_b1=(float*)(s_mem+40960);
  float* s_w2=(float*)(s_mem+41472);
  float* s_fg0=(float*)(s_mem+41984);                      // 288 f
  float* s_red=(float*)(s_mem+43136);
  unsigned short* scr=(unsigned short*)(s_mem+43200)+(size_t)wv*2048;  // 4KB/wave (g hi|lo)
  for (int j=tid;j<2048;j+=256) ((int4*)s_w1)[j]=((const int4*)enw1p)[j];
  if (tid<128){ s_b1[tid]=b1[tid]; s_w2[tid]=w2[tid]; }
  for (int j=tid;j<288;j+=256) s_fg0[j]=fg[j];
  { int4 z={0,0,0,0}; for (int j=tid;j<512;j+=256) ((int4*)s_xn)[j]=z; }
  __syncthreads();
  {
    const float* xr=xn+(size_t)n*1600;
    for (int j=tid;j<1600;j+=256){
      int k=j>>6, c=j&63;
      float v=xr[j];
      unsigned short h=f2bf(v);
      s_xn[c*32+k]=h;
      s_xn[2048+c*32+k]=f2bf(v-bf2f(h));
    }
  }
  __syncthreads();
  bf16x8 XBh[4],XBl[4];
  #pragma unroll
  for (int ct=0;ct<4;ct++){
    int o=(ct*16+lanelo)*32 + khi*8;
    XBh[ct]=*(const bf16x8*)(s_xn+o);
    XBl[ct]=*(const bf16x8*)(s_xn+2048+o);
  }
  float b2v=b2[0];
  float e=0.0f;
  for (int t=wv;t<18;t+=4){
    bf16x8 Atgh=*(const bf16x8*)(tgp + t*512 + lane*8);
    bf16x8 Atgl=*(const bf16x8*)(tgp + 9216 + t*512 + lane*8);
    #pragma unroll
    for (int ct=0;ct<4;ct++){
      f32x4 g={0,0,0,0};
      g=__builtin_amdgcn_mfma_f32_16x16x32_bf16(Atgh,XBh[ct],g,0,0,0);
      g=__builtin_amdgcn_mfma_f32_16x16x32_bf16(Atgl,XBh[ct],g,0,0,0);
      g=__builtin_amdgcn_mfma_f32_16x16x32_bf16(Atgh,XBl[ct],g,0,0,0);
      #pragma unroll
      for (int q=0;q<4;q++){
        int row=khi*4+q, col=ct*16+lanelo;
        int pos=row*64 + (((col>>3)^(row&7))<<3) + (col&7);
        float v=g[q]; unsigned short h=f2bf(v);
        scr[pos]=h; scr[1024+pos]=f2bf(v-bf2f(h));
      }
    }
    bf16x8 Agh[2],Agl[2];
    #pragma unroll
    for (int kt=0;kt<2;kt++){
      int o=lanelo*64 + (((kt*4+khi)^(lanelo&7))<<3);
      Agh[kt]=*(const bf16x8*)(scr+o);
      Agl[kt]=*(const bf16x8*)(scr+1024+o);
    }
    #pragma unroll
    for (int nt=0;nt<8;nt++){
      f32x4 h={0,0,0,0};
      #pragma unroll
      for (int kt=0;kt<2;kt++){
        bf16x8 Bh=*(const bf16x8*)(s_w1 + (kt*8+nt)*512 + lane*8);
        bf16x8 Bl=*(const bf16x8*)(s_w1 + 8192 + (kt*8+nt)*512 + lane*8);
        h=__builtin_amdgcn_mfma_f32_16x16x32_bf16(Agh[kt],Bh,h,0,0,0);
        h=__builtin_amdgcn_mfma_f32_16x16x32_bf16(Agl[kt],Bh,h,0,0,0);
        h=__builtin_amdgcn_mfma_f32_16x16x32_bf16(Agh[kt],Bl,h,0,0,0);
      }
      #pragma unroll
      for (int q=0;q<4;q++){
        int row=khi*4+q, col=nt*16+lanelo;
        float v=silu_f(h[q]+s_b1[col]);
        e += v*s_w2[col]*s_fg0[t*16+row];
      }
    }
    if (lanelo==0){
      #pragma unroll
      for (int q=0;q<4;q++) e += s_fg0[t*16+khi*4+q]*b2v;
    }
  }
  #pragma unroll
  for (int d=1;d<64;d<<=1) e += __shfl_xor(e,d);
  if (lane==0) s_red[wv]=e;
  __syncthreads();
  if (tid==0) out[n]=(s_red[0]+s_red[1]+s_red[2]+s_red[3])*(1.0f/2000.0f);
}

extern "C" void kernel_launch(void* const* d_in, const int* in_sizes, int n_in,
                              void* d_out, int out_size, void* d_ws, size_t ws_size,
                              hipStream_t stream){
  (void)n_in; (void)out_size; (void)ws_size;
  const float* ev   = (const float*)d_in[0];
  const float* wig  = (const float*)d_in[1];
  const float* winv = (const float*)d_in[2];
  const float* spe  = (const float*)d_in[3];
  const float* ese  = (const float*)d_in[4];
  const float* degW1= (const float*)d_in[5];
  const float* degb1= (const float*)d_in[6];
  const float* degW2= (const float*)d_in[7];
  const float* degb2= (const float*)d_in[8];
  const float* n1w  = (const float*)d_in[9];
  const float* radW1= (const float*)d_in[10];
  const float* radb1= (const float*)d_in[11];
  const float* radW2= (const float*)d_in[12];
  const float* radb2= (const float*)d_in[13];
  const float* so2W = (const float*)d_in[14];
  const float* aW   = (const float*)d_in[15];
  const float* aV   = (const float*)d_in[16];
  const float* vW   = (const float*)d_in[17];
  const float* pW   = (const float*)d_in[18];
  const float* n2w  = (const float*)d_in[19];
  const float* fW1  = (const float*)d_in[20];
  const float* fb1  = (const float*)d_in[21];
  const float* fW2  = (const float*)d_in[22];
  const float* tg   = (const float*)d_in[23];
  const float* fg   = (const float*)d_in[24];
  const float* fnw  = (const float*)d_in[25];
  const float* enW1 = (const float*)d_in[26];
  const float* enb1 = (const float*)d_in[27];
  const float* enW2 = (const float*)d_in[28];
  const float* enb2 = (const float*)d_in[29];
  const int* nsp = (const int*)d_in[30];
  const int* snd = (const int*)d_in[31];
  const int* rcv = (const int*)d_in[32];
  int N = in_sizes[30];
  int E = in_sizes[31];
  float* out = (float*)d_out;

  float* ws = (float*)d_ws;
  size_t off = 0;
  float* radbuf = ws + off; off += (size_t)E*384;
  float* logits = ws + off; off += (size_t)E*8;
  float* mx     = ws + off; off += (size_t)N*8;
  float* den    = ws + off; off += (size_t)N*8;
  float* x      = ws + off; off += (size_t)N*1600;
  float* xn     = ws + off; off += (size_t)N*1600;
  unsigned short* wsvb  = (unsigned short*)(ws + off); off += (size_t)6*16384/2;
  unsigned short* projb = (unsigned short*)(ws + off); off += (size_t)6*8192/2;
  int* cnt      = (int*)(ws + off); off += (size_t)N;
  int* rowptr   = (int*)(ws + off); off += (size_t)(N+1);
  int* fill     = (int*)(ws + off); off += (size_t)N;
  int* eixbuf   = (int*)(ws + off); off += (size_t)E;
  off = (off + 3) & ~((size_t)3);                       // 16B-align
  unsigned short* oebuf = (unsigned short*)(ws + off); off += (size_t)E*608;  // [E][19][64] bf16
  unsigned short* tgp   = (unsigned short*)(ws + off); off += 9216;    // hi+lo 18432 shorts
  unsigned short* fgp   = (unsigned short*)(ws + off); off += 18432;   // hi+lo 36864 shorts
  unsigned short* wwp   = (unsigned short*)(ws + off); off += 32768;   // 2 layers x (w1 hi/lo + w2 hi/lo)
  unsigned short* enw1p = (unsigned short*)(ws + off); off += 8192;    // hi+lo 16384 shorts
  // MLP weight fragment packs (hi|lo contiguous planes)
  unsigned short* degw1p = (unsigned short*)(ws + off); off += 94208;   // 23*8*512 *2 = 188416 shorts
  unsigned short* degw2p = (unsigned short*)(ws + off); off += 155648;  // 4*76*512 *2 = 311296 shorts
  unsigned short* radw1p = (unsigned short*)(ws + off); off += 94208*2; // per layer 188416 shorts
  unsigned short* radw2p = (unsigned short*)(ws + off); off += 49152*2; // per layer 4*24*512*2=98304 shorts

  // CSR by receiver + packed weights
  zero_cnt_kernel<<<(N+255)/256, 256, 0, stream>>>(cnt, N);
  csr_count_kernel<<<(E+255)/256, 256, 0, stream>>>(rcv, cnt, E);
  csr_scan_kernel<<<1, 256, 0, stream>>>(cnt, rowptr, fill, N);
  csr_fill_kernel<<<(E+255)/256, 256, 0, stream>>>(rcv, fill, eixbuf, E);
  wsvb_kernel<<<6, 256, 0, stream>>>(so2W, vW, wsvb);
  projb_kernel<<<6, 256, 0, stream>>>(pW, projb);
  pack_tg2_kernel<<<1, 256, 0, stream>>>(tg, tgp);
  pack_fg2_kernel<<<1, 256, 0, stream>>>(fg, fgp);
  for (int i=0;i<2;i++){
    unsigned short* wl = wwp + (size_t)i*32768;
    packB2g_kernel<<<8, 256, 0, stream>>>(fW1 + (size_t)i*8192, wl, wl+8192, 64, 128);
    packB2g_kernel<<<8, 256, 0, stream>>>(fW2 + (size_t)i*8192, wl+16384, wl+24576, 128, 64);
  }
  packB2g_kernel<<<8, 256, 0, stream>>>(enW1, enw1p, enw1p+8192, 64, 128);
  packB2g_kernel<<<32, 256, 0, stream>>>(degW1, degw1p, degw1p+94208, DIN, 128);
  packB2g_kernel<<<32, 256, 0, stream>>>(degW2, degw2p, degw2p+155648, 128, 1216);
  for (int i=0;i<2;i++){
    unsigned short* r1 = radw1p + (size_t)i*188416;
    unsigned short* r2 = radw2p + (size_t)i*98304;
    packB2g_kernel<<<32, 256, 0, stream>>>(radW1 + (size_t)i*DIN*128, r1, r1+94208, DIN, 128);
    packB2g_kernel<<<16, 256, 0, stream>>>(radW2 + (size_t)i*128*384, r2, r2+49152, 128, 384);
  }

  // edge degree embedding: edge-parallel MFMA MLP (CSR-ordered) + per-node rotate/scatter
  mlp_edge_kernel<<<(E+15)/16, 256, 0, stream>>>(ev, ese, nsp,
      degw1p, degw1p+94208, degb1, degw2p, degw2p+155648, degb2,
      snd, rcv, eixbuf, 1, 76, 0, oebuf, (float*)0, E);
  deg_sum_kernel<<<N, 256, 0, stream>>>(oebuf, winv, rowptr, eixbuf, nsp, spe, x, N);

  for (int i=0;i<2;i++){
    rmsnorm_kernel<<<N, 256, 0, stream>>>(x, n1w + (size_t)i*320, xn, N);
    init_mxden_kernel<<<(N*8+255)/256, 256, 0, stream>>>(mx, den, N);
    {
      unsigned short* r1 = radw1p + (size_t)i*188416;
      unsigned short* r2 = radw2p + (size_t)i*98304;
      mlp_edge_kernel<<<(E+15)/16, 256, 0, stream>>>(ev, ese, nsp,
          r1, r1+94208, radb1 + (size_t)i*128, r2, r2+49152, radb2 + (size_t)i*384,
          snd, rcv, eixbuf, 0, 24, 1, (unsigned short*)0, radbuf, E);
    }
    logits_kernel<<<E, 256, 0, stream>>>(xn, wig, radbuf, so2W + (size_t)i*24576,
                                         aW + (size_t)i*64*256, aV + (size_t)i*256,
                                         snd, rcv, logits, mx, E);
    den_kernel<<<(E*8+255)/256, 256, 0, stream>>>(logits, mx, rcv, den, E);
    attn_edge_kernel<<<(E+3)/4, 256, 0, stream>>>(xn, wig, radbuf,
                                                  wsvb + (size_t)i*3*16384, projb + (size_t)i*3*8192,
                                                  logits, mx, den, snd, rcv, eixbuf, oebuf, E);
    attn_sum_kernel<<<N, 256, 0, stream>>>(oebuf, winv, rowptr, eixbuf, x, N);
    rmsnorm_kernel<<<N, 256, 0, stream>>>(x, n2w + (size_t)i*320, xn, N);
    grid_ffn_mfma_kernel<<<N, 256, 0, stream>>>(xn, tgp, fgp,
                                                wwp + (size_t)i*32768, wwp + (size_t)i*32768 + 16384,
                                                fb1 + (size_t)i*128, x, N);
  }
  rmsnorm_kernel<<<N, 256, 0, stream>>>(x, fnw, xn, N);
  energy_mfma_kernel<<<N, 256, 0, stream>>>(xn, tgp, fg, enw1p, enb1, enW2, enb2, out, N);
}